// Round 6
// baseline (61094.714 us; speedup 1.0000x reference)
//
#include <hip/hip_runtime.h>

typedef unsigned int  uint32;
typedef unsigned long long u64;
typedef unsigned short bf16u;
typedef __attribute__((ext_vector_type(8))) short s8v;    // 8 bf16 (4 VGPRs)
typedef __attribute__((ext_vector_type(4))) float f4v;    // MFMA acc

__device__ __forceinline__ float fast_tanh(float x) {
    x = fminf(9.f, fmaxf(-9.f, x));
    float e = __expf(2.f * x);
    return (e - 1.f) / (e + 1.f);
}
__device__ __forceinline__ float sigmoidf(float x) {
    return 1.f / (1.f + __expf(-x));
}
__device__ __forceinline__ bf16u f2bf(float f) {
    uint32 u = __float_as_uint(f);
    u += 0x7fffu + ((u >> 16) & 1u);
    return (bf16u)(u >> 16);
}
__device__ __forceinline__ float bf2f(bf16u u) {
    return __uint_as_float(((uint32)u) << 16);
}
__device__ __forceinline__ uint32 pack2bf(float lo, float hi) {
    return (uint32)f2bf(lo) | ((uint32)f2bf(hi) << 16);
}
__device__ __forceinline__ float bflo(uint32 p) { return __uint_as_float(p << 16); }
__device__ __forceinline__ float bfhi(uint32 p) { return __uint_as_float(p & 0xffff0000u); }

// ---------------------------------------------------------------------------
// Embedding + context projection -> inp [rt=t*32+b][256] bf16 (emb || ctx)
// ---------------------------------------------------------------------------
__global__ void __launch_bounds__(128) embed_ctx_kernel(
    const int* __restrict__ x, const float* __restrict__ ctx,
    const float* __restrict__ emb, const float* __restrict__ ctxW,
    const float* __restrict__ ctxb, bf16u* __restrict__ inp)
{
    const int r0 = blockIdx.x * 16;
    const int tid = threadIdx.x;
    __shared__ float cs[16][301];
    __shared__ int xs[16];
    for (int i = tid; i < 16 * 300; i += 128) {
        int row = i / 300, k = i - row * 300;
        int rt = r0 + row, b = rt & 31, t = rt >> 5;
        cs[row][k] = ctx[((size_t)b * 1024 + t) * 300 + k];
    }
    if (tid < 16) {
        int rt = r0 + tid;
        xs[tid] = x[(rt & 31) * 1024 + (rt >> 5)];
    }
    __syncthreads();
    float acc[16];
    #pragma unroll
    for (int row = 0; row < 16; ++row) acc[row] = 0.f;
    for (int k = 0; k < 300; ++k) {
        float w = ctxW[tid * 300 + k];
        #pragma unroll
        for (int row = 0; row < 16; ++row) acc[row] = fmaf(w, cs[row][k], acc[row]);
    }
    float bb = ctxb[tid];
    for (int row = 0; row < 16; ++row) {
        size_t base = (size_t)(r0 + row) * 256;
        inp[base + tid]       = f2bf(emb[xs[row] * 128 + tid]);
        inp[base + 128 + tid] = f2bf(acc[row] + bb);
    }
}

// ---------------------------------------------------------------------------
// MFMA GEMM: C[M,N] = A[M,K](bf16) @ W[N,K]^T(f32, split hi/lo bf16)
// A split at K0 between A0/A1 (both bf16, row strides K0 / K-K0).
// mode 0: f32 out TRANSPOSED -> Cout[col*ldc + row]  (for gxT)
// mode 1: bf16 out; mode 2: bf16+tanh; mode 3: f32 out, row rt->(b*1024+t).
// BM=BN=64, BK=32; 4 waves, each a 32x32 quadrant via 2x2 16x16x32 MFMAs.
// ---------------------------------------------------------------------------
__global__ void __launch_bounds__(256) gemm_kernel(
    const bf16u* __restrict__ A0, const bf16u* __restrict__ A1, int K0,
    const float* __restrict__ W, const float* __restrict__ bias1,
    const float* __restrict__ bias2, void* __restrict__ Cout,
    int M, int N, int K, int mode, int ldc)
{
    __shared__ bf16u As[64][40];     // row stride 40 bf16 = 80 B (2-way max)
    __shared__ bf16u Whi[64][40];
    __shared__ bf16u Wlo[64][40];
    const int tid = threadIdx.x;
    const int bn = blockIdx.x * 64, bm = blockIdx.y * 64;
    const int wave = tid >> 6, lane = tid & 63;
    const int wm = wave >> 1, wn = wave & 1;
    const int ncol = lane & 15, quad = lane >> 4;
    const int lr = tid >> 2, lk = (tid & 3) * 8;   // loader: row, k-offset

    f4v acc[2][2];
    #pragma unroll
    for (int i = 0; i < 2; ++i)
        #pragma unroll
        for (int j = 0; j < 2; ++j) acc[i][j] = (f4v){0.f, 0.f, 0.f, 0.f};

    const int wrow = bn + lr;
    for (int k0 = 0; k0 < K; k0 += 32) {
        const bf16u* Ab; int kb, lda;
        if (k0 < K0) { Ab = A0; kb = k0; lda = K0; }
        else         { Ab = A1; kb = k0 - K0; lda = K - K0; }
        uint4 av = *(const uint4*)(Ab + (size_t)(bm + lr) * lda + kb + lk);
        float4 w0 = make_float4(0.f, 0.f, 0.f, 0.f), w1 = w0;
        if (wrow < N) {
            const float* wp = W + (size_t)wrow * K + k0 + lk;
            w0 = *(const float4*)wp;
            w1 = *(const float4*)(wp + 4);
        }
        __syncthreads();
        *(uint4*)&As[lr][lk] = av;
        {
            bf16u h[8], l[8];
            float wf[8] = {w0.x, w0.y, w0.z, w0.w, w1.x, w1.y, w1.z, w1.w};
            #pragma unroll
            for (int j = 0; j < 8; ++j) {
                h[j] = f2bf(wf[j]);
                l[j] = f2bf(wf[j] - bf2f(h[j]));
            }
            #pragma unroll
            for (int j = 0; j < 8; ++j) Whi[lr][lk + j] = h[j];
            #pragma unroll
            for (int j = 0; j < 8; ++j) Wlo[lr][lk + j] = l[j];
        }
        __syncthreads();
        s8v aF[2], bH[2], bL[2];
        #pragma unroll
        for (int mt = 0; mt < 2; ++mt)
            aF[mt] = *(const s8v*)&As[wm * 32 + mt * 16 + ncol][quad * 8];
        #pragma unroll
        for (int nt = 0; nt < 2; ++nt) {
            bH[nt] = *(const s8v*)&Whi[wn * 32 + nt * 16 + ncol][quad * 8];
            bL[nt] = *(const s8v*)&Wlo[wn * 32 + nt * 16 + ncol][quad * 8];
        }
        #pragma unroll
        for (int mt = 0; mt < 2; ++mt)
            #pragma unroll
            for (int nt = 0; nt < 2; ++nt) {
                acc[mt][nt] = __builtin_amdgcn_mfma_f32_16x16x32_bf16(
                    aF[mt], bH[nt], acc[mt][nt], 0, 0, 0);
                acc[mt][nt] = __builtin_amdgcn_mfma_f32_16x16x32_bf16(
                    aF[mt], bL[nt], acc[mt][nt], 0, 0, 0);
            }
    }

    #pragma unroll
    for (int nt = 0; nt < 2; ++nt) {
        const int col = bn + wn * 32 + nt * 16 + ncol;
        if (col >= N) continue;
        float bb = 0.f;
        if (bias1) bb += bias1[col];
        if (bias2) bb += bias2[col];
        #pragma unroll
        for (int mt = 0; mt < 2; ++mt) {
            const int rowb = bm + wm * 32 + mt * 16 + quad * 4;
            if (mode == 0) {
                float4 v;
                v.x = acc[mt][nt][0] + bb;
                v.y = acc[mt][nt][1] + bb;
                v.z = acc[mt][nt][2] + bb;
                v.w = acc[mt][nt][3] + bb;
                *(float4*)((float*)Cout + (size_t)col * ldc + rowb) = v;
            } else if (mode == 3) {
                #pragma unroll
                for (int r = 0; r < 4; ++r) {
                    int row = rowb + r;
                    int b = row & 31, t = row >> 5;
                    ((float*)Cout)[((size_t)b * 1024 + t) * (size_t)N + col] =
                        acc[mt][nt][r] + bb;
                }
            } else {
                #pragma unroll
                for (int r = 0; r < 4; ++r) {
                    float v = acc[mt][nt][r] + bb;
                    if (mode == 2) v = fast_tanh(v);
                    ((bf16u*)Cout)[(size_t)(rowb + r) * N + col] = f2bf(v);
                }
            }
        }
    }
}

// ---------------------------------------------------------------------------
// Flag barrier, 24 blocks. ONE FLAG PER 128-B CACHE LINE (flags[bid*32]) so
// polls on other blocks' flags never collide with a store's line. Lanes
// 0..23 poll 24 distinct lines in parallel. Monotonic rounds, no reset.
// __syncthreads() before the store drains vmcnt(0) -> prior agent-scope
// h-stores are at the coherence point before the flag becomes visible.
// ---------------------------------------------------------------------------
__device__ __forceinline__ void flag_barrier(uint32* flags, uint32 r,
                                             int tid, int bid) {
    __syncthreads();
    if (tid == 0)
        __hip_atomic_store(&flags[bid * 32], r, __ATOMIC_RELAXED, __HIP_MEMORY_SCOPE_AGENT);
    if (tid < 24) {
        while (__hip_atomic_load(&flags[tid * 32], __ATOMIC_RELAXED,
                                 __HIP_MEMORY_SCOPE_AGENT) < r)
            __builtin_amdgcn_s_sleep(1);
    }
    __syncthreads();
}

// ---------------------------------------------------------------------------
// LSTM, one 128-step chunk. 24 blocks x 256 threads. Block owns 16 hidden
// dims (64 gate rows); wave w = gate w (rows w*16..w*16+15). Whh slice in
// registers as hi/lo bf16 B-frags (96 VGPR/wave). h in hbuf[parity][plane]
// [32 b][192 u32]; MFMA A-frags loaded directly from global via relaxed
// agent-scope u64 loads. Cell update: all 256 threads, 2 dims each.
// ---------------------------------------------------------------------------
__global__ void __launch_bounds__(256, 1) lstm_chunk_kernel(
    const float* __restrict__ gxT,   // [1536][4096] fp32 (chunk, col=tl*32+b)
    const float* __restrict__ Whh,   // [1536][384] fp32
    const float* __restrict__ h0, const float* __restrict__ c0,
    bf16u* __restrict__ y,           // [t*32+b][384] bf16
    uint32* __restrict__ hbuf,       // [2][2][32][192] u32
    float* __restrict__ cbuf, uint32* __restrict__ flags,
    int roundBase, int t0, int is_first, int is_last,
    float* __restrict__ hs_out, float* __restrict__ cs_out)
{
    const int tid = threadIdx.x, bid = blockIdx.x;   // 24 blocks
    const int j0 = bid * 16;
    const int w = tid >> 6;                          // wave = gate index 0..3
    const int lane = tid & 63;
    const int ncol = lane & 15, quad = lane >> 4;    // ncol = dim within block
    const int wrow = w * 384 + j0 + ncol;            // Whh row for B-frag

    __shared__ float gates_s[64][33];                // [gate*16+dim][batch]

    // ---- B fragments: Whh rows split hi/lo bf16 (once per launch) ----
    s8v Bhi[12], Blo[12];
    #pragma unroll
    for (int kt = 0; kt < 12; ++kt) {
        const float* wp = Whh + (size_t)wrow * 384 + kt * 32 + quad * 8;
        s8v hi, lo;
        #pragma unroll
        for (int j = 0; j < 8; ++j) {
            float wv = wp[j];
            bf16u wh = f2bf(wv);
            bf16u wl = f2bf(wv - bf2f(wh));
            hi[j] = (short)wh; lo[j] = (short)wl;
        }
        Bhi[kt] = hi; Blo[kt] = lo;
    }

    // update mapping: all 256 threads own (batch ub, dim-pair jg0=j0+2*jp)
    const int ub = tid & 31, jp = tid >> 5;          // jp 0..7
    const int jg0 = j0 + 2 * jp;
    const int wcol = bid * 8 + jp;                   // u32 column in planes
    float c0r = 0.f, c1r = 0.f, h0l = 0.f, h1l = 0.f;

    if (is_first) {
        float ha = h0[ub * 384 + jg0], hb = h0[ub * 384 + jg0 + 1];
        bf16u ha_h = f2bf(ha); bf16u ha_l = f2bf(ha - bf2f(ha_h));
        bf16u hb_h = f2bf(hb); bf16u hb_l = f2bf(hb - bf2f(hb_h));
        __hip_atomic_store(&hbuf[(0 * 32 + ub) * 192 + wcol],
                           (uint32)ha_h | ((uint32)hb_h << 16),
                           __ATOMIC_RELAXED, __HIP_MEMORY_SCOPE_AGENT);
        __hip_atomic_store(&hbuf[(32 + ub) * 192 + wcol],
                           (uint32)ha_l | ((uint32)hb_l << 16),
                           __ATOMIC_RELAXED, __HIP_MEMORY_SCOPE_AGENT);
        c0r = c0[ub * 384 + jg0];
        c1r = c0[ub * 384 + jg0 + 1];
    } else {
        c0r = cbuf[ub * 384 + jg0];
        c1r = cbuf[ub * 384 + jg0 + 1];
    }
    flag_barrier(flags, (uint32)(roundBase + 1), tid, bid);

    for (int tl = 0; tl < 128; ++tl) {
        const int t = t0 + tl;
        const uint32* hR = hbuf + (t & 1) * (2 * 32 * 192);
        uint32* hW = hbuf + ((t + 1) & 1) * (2 * 32 * 192);

        // gx prefetch for the update role (plain loads, L2-hot, coalesced)
        float gxv[8];
        #pragma unroll
        for (int g = 0; g < 4; ++g) {
            gxv[g]     = gxT[(size_t)(g * 384 + jg0) * 4096 + tl * 32 + ub];
            gxv[4 + g] = gxT[(size_t)(g * 384 + jg0 + 1) * 4096 + tl * 32 + ub];
        }

        // ---- MFMA: gates[64 rows x 32 b] = h x Whh^T (hi/lo split) ----
        // m-tiles: batch rows ncol and 16+ncol; n: this wave's gate rows.
        const u64* hi0 = (const u64*)(hR + (size_t)ncol * 192);
        const u64* lo0 = (const u64*)(hR + (size_t)(32 + ncol) * 192);
        const u64* hi1 = (const u64*)(hR + (size_t)(16 + ncol) * 192);
        const u64* lo1 = (const u64*)(hR + (size_t)(32 + 16 + ncol) * 192);
        f4v aHH0 = {0.f,0.f,0.f,0.f}, aLH0 = aHH0, aHL0 = aHH0;
        f4v aHH1 = aHH0, aLH1 = aHH0, aHL1 = aHH0;
        #pragma unroll
        for (int kt = 0; kt < 12; ++kt) {
            const int q0i = (kt * 16 + quad * 4) >> 1;   // u64 index
            union { u64 q[2]; s8v v; } Ah0, Al0, Ah1, Al1;
            Ah0.q[0] = __hip_atomic_load(hi0 + q0i,     __ATOMIC_RELAXED, __HIP_MEMORY_SCOPE_AGENT);
            Ah0.q[1] = __hip_atomic_load(hi0 + q0i + 1, __ATOMIC_RELAXED, __HIP_MEMORY_SCOPE_AGENT);
            Al0.q[0] = __hip_atomic_load(lo0 + q0i,     __ATOMIC_RELAXED, __HIP_MEMORY_SCOPE_AGENT);
            Al0.q[1] = __hip_atomic_load(lo0 + q0i + 1, __ATOMIC_RELAXED, __HIP_MEMORY_SCOPE_AGENT);
            Ah1.q[0] = __hip_atomic_load(hi1 + q0i,     __ATOMIC_RELAXED, __HIP_MEMORY_SCOPE_AGENT);
            Ah1.q[1] = __hip_atomic_load(hi1 + q0i + 1, __ATOMIC_RELAXED, __HIP_MEMORY_SCOPE_AGENT);
            Al1.q[0] = __hip_atomic_load(lo1 + q0i,     __ATOMIC_RELAXED, __HIP_MEMORY_SCOPE_AGENT);
            Al1.q[1] = __hip_atomic_load(lo1 + q0i + 1, __ATOMIC_RELAXED, __HIP_MEMORY_SCOPE_AGENT);
            aHH0 = __builtin_amdgcn_mfma_f32_16x16x32_bf16(Ah0.v, Bhi[kt], aHH0, 0, 0, 0);
            aLH0 = __builtin_amdgcn_mfma_f32_16x16x32_bf16(Al0.v, Bhi[kt], aLH0, 0, 0, 0);
            aHL0 = __builtin_amdgcn_mfma_f32_16x16x32_bf16(Ah0.v, Blo[kt], aHL0, 0, 0, 0);
            aHH1 = __builtin_amdgcn_mfma_f32_16x16x32_bf16(Ah1.v, Bhi[kt], aHH1, 0, 0, 0);
            aLH1 = __builtin_amdgcn_mfma_f32_16x16x32_bf16(Al1.v, Bhi[kt], aLH1, 0, 0, 0);
            aHL1 = __builtin_amdgcn_mfma_f32_16x16x32_bf16(Ah1.v, Blo[kt], aHL1, 0, 0, 0);
        }
        const int nrow = w * 16 + ncol;
        #pragma unroll
        for (int r = 0; r < 4; ++r) {
            gates_s[nrow][quad * 4 + r]      = aHH0[r] + aLH0[r] + aHL0[r];
            gates_s[nrow][16 + quad * 4 + r] = aHH1[r] + aLH1[r] + aHL1[r];
        }
        __syncthreads();

        // ---- cell update: all 256 threads, two hidden dims each ----
        {
            const int jj0 = 2 * jp, jj1 = 2 * jp + 1;
            float pi0 = gates_s[jj0][ub]      + gxv[0];
            float pf0 = gates_s[16 + jj0][ub] + gxv[1];
            float pg0 = gates_s[32 + jj0][ub] + gxv[2];
            float po0 = gates_s[48 + jj0][ub] + gxv[3];
            float pi1 = gates_s[jj1][ub]      + gxv[4];
            float pf1 = gates_s[16 + jj1][ub] + gxv[5];
            float pg1 = gates_s[32 + jj1][ub] + gxv[6];
            float po1 = gates_s[48 + jj1][ub] + gxv[7];
            c0r = sigmoidf(pf0) * c0r + sigmoidf(pi0) * fast_tanh(pg0);
            c1r = sigmoidf(pf1) * c1r + sigmoidf(pi1) * fast_tanh(pg1);
            float hv0 = sigmoidf(po0) * fast_tanh(c0r);
            float hv1 = sigmoidf(po1) * fast_tanh(c1r);
            h0l = hv0; h1l = hv1;
            bf16u h0h = f2bf(hv0); bf16u h0lo = f2bf(hv0 - bf2f(h0h));
            bf16u h1h = f2bf(hv1); bf16u h1lo = f2bf(hv1 - bf2f(h1h));
            __hip_atomic_store(&hW[(0 * 32 + ub) * 192 + wcol],
                               (uint32)h0h | ((uint32)h1h << 16),
                               __ATOMIC_RELAXED, __HIP_MEMORY_SCOPE_AGENT);
            __hip_atomic_store(&hW[(32 + ub) * 192 + wcol],
                               (uint32)h0lo | ((uint32)h1lo << 16),
                               __ATOMIC_RELAXED, __HIP_MEMORY_SCOPE_AGENT);
            *(uint32*)(y + ((size_t)t * 32 + ub) * 384 + jg0) =
                (uint32)h0h | ((uint32)h1h << 16);
        }
        flag_barrier(flags, (uint32)(roundBase + tl + 2), tid, bid);
    }

    cbuf[ub * 384 + jg0]     = c0r;
    cbuf[ub * 384 + jg0 + 1] = c1r;
    if (is_last) {
        hs_out[ub * 384 + jg0]     = h0l;
        hs_out[ub * 384 + jg0 + 1] = h1l;
        cs_out[ub * 384 + jg0]     = c0r;
        cs_out[ub * 384 + jg0 + 1] = c1r;
    }
}

// ---------------------------------------------------------------------------
// Causal flash attention, bf16 in/out (unchanged from passing round).
// ---------------------------------------------------------------------------
__global__ void __launch_bounds__(256) attn_kernel(
    const bf16u* __restrict__ outy, const bf16u* __restrict__ keys,
    bf16u* __restrict__ ctxv)
{
    const int b = blockIdx.y;
    const int q0 = blockIdx.x * 32;
    const int tid = threadIdx.x;
    __shared__ uint32 Qs[32][194];
    __shared__ uint32 Ks[16][194];
    __shared__ uint32 Vs[16][192];
    __shared__ float Ss[32][16];
    __shared__ float m_s[32], l_s[32], alpha_s[32];

    for (int i = tid; i < 32 * 192; i += 256) {
        int q = i / 192, dp = i - q * 192;
        Qs[q][dp] = ((const uint32*)(outy + ((size_t)(q0 + q) * 32 + b) * 384))[dp];
    }
    if (tid < 32) { m_s[tid] = -3e38f; l_s[tid] = 0.f; }

    const int qo = tid >> 3, dg = tid & 7;
    float O[48];
    #pragma unroll
    for (int d = 0; d < 48; ++d) O[d] = 0.f;

    const int nkt = (q0 + 32) >> 4;
    for (int kt = 0; kt < nkt; ++kt) {
        const int k0 = kt * 16;
        __syncthreads();
        for (int i = tid; i < 16 * 192; i += 256) {
            int kk = i / 192, dp = i - kk * 192;
            size_t rt = (size_t)(k0 + kk) * 32 + b;
            Ks[kk][dp] = ((const uint32*)(keys + rt * 384))[dp];
            Vs[kk][dp] = ((const uint32*)(outy + rt * 384))[dp];
        }
        __syncthreads();
        #pragma unroll
        for (int pp = 0; pp < 2; ++pp) {
            int p = tid + pp * 256;
            int q = p >> 4, k = p & 15;
            const uint32* qrow = Qs[q];
            const uint32* krow = Ks[k];
            float acc = 0.f;
            for (int dp = 0; dp < 192; ++dp) {
                uint32 qa = qrow[dp], ka = krow[dp];
                acc = fmaf(bflo(qa), bflo(ka), acc);
                acc = fmaf(bfhi(qa), bfhi(ka), acc);
            }
            acc *= 0.051031036307982884f;    // 1/sqrt(384)
            Ss[q][k] = ((k0 + k) <= (q0 + q)) ? acc : -1e30f;
        }
        __syncthreads();
        if (tid < 32) {
            int q = tid;
            float mt = m_s[q];
            #pragma unroll
            for (int k = 0; k < 16; ++k) mt = fmaxf(mt, Ss[q][k]);
            float alpha = __expf(m_s[q] - mt);
            float l = l_s[q] * alpha;
            #pragma unroll
            for (int k = 0; k < 16; ++k) {
                float pv = __expf(Ss[q][k] - mt);
                Ss[q][k] = pv;
                l += pv;
            }
            m_s[q] = mt; l_s[q] = l; alpha_s[q] = alpha;
        }
        __syncthreads();
        {
            float al = alpha_s[qo];
            #pragma unroll
            for (int d = 0; d < 48; ++d) O[d] *= al;
            for (int k = 0; k < 16; ++k) {
                float pv = Ss[qo][k];
                const uint32* vrow = Vs[k] + dg * 24;
                #pragma unroll
                for (int dp = 0; dp < 24; ++dp) {
                    uint32 va = vrow[dp];
                    O[2 * dp]     = fmaf(pv, bflo(va), O[2 * dp]);
                    O[2 * dp + 1] = fmaf(pv, bfhi(va), O[2 * dp + 1]);
                }
            }
        }
    }
    float inv = 1.f / l_s[qo];
    uint32* dst = (uint32*)(ctxv + ((size_t)(q0 + qo) * 32 + b) * 384) + dg * 24;
    #pragma unroll
    for (int dp = 0; dp < 24; ++dp)
        dst[dp] = pack2bf(O[2 * dp] * inv, O[2 * dp + 1] * inv);
}

// ---------------------------------------------------------------------------
extern "C" void kernel_launch(void* const* d_in, const int* in_sizes, int n_in,
                              void* d_out, int out_size, void* d_ws, size_t ws_size,
                              hipStream_t stream) {
    (void)in_sizes; (void)n_in; (void)out_size; (void)ws_size;
    const int*   x        = (const int*)d_in[0];
    const float* context  = (const float*)d_in[1];
    const float* h_in     = (const float*)d_in[2];
    const float* c_in     = (const float*)d_in[3];
    const float* emb      = (const float*)d_in[4];
    const float* ctx_W    = (const float*)d_in[5];
    const float* ctx_b    = (const float*)d_in[6];
    const float* Wih0     = (const float*)d_in[7];
    const float* Wih_rest = (const float*)d_in[8];
    const float* Whh      = (const float*)d_in[9];
    const float* bih      = (const float*)d_in[10];
    const float* bhh      = (const float*)d_in[11];
    const float* Wa       = (const float*)d_in[12];
    const float* comb_W   = (const float*)d_in[13];
    const float* comb_b   = (const float*)d_in[14];
    const float* fc_W     = (const float*)d_in[15];
    const float* fc_b     = (const float*)d_in[16];
    float* out = (float*)d_out;

    // ---- workspace layout ----
    char* wsb = (char*)d_ws;
    uint32* flags = (uint32*)(wsb + 0);               //   3 KB (24 x 128-B lines)
    uint32* hbuf  = (uint32*)(wsb + 4096);            //  96 KB [2][2][32][192]
    float*  cbuf  = (float*)(wsb + 102400);           //  48 KB [32][384]
    bf16u*  inp   = (bf16u*)(wsb + 153600);           //  16.78 MB [32768,256]
    bf16u*  yA    = (bf16u*)(wsb + 16930816ull);      //  25.17 MB [32768,384]
    bf16u*  yB    = (bf16u*)(wsb + 42096640ull);      //  25.17 MB [32768,384]
    float*  gxT   = (float*)(wsb + 67262464ull);      //  25.17 MB [1536,4096]
    bf16u* keysu = (bf16u*)gxT;                       // reuse after LSTM stack
    bf16u* ctxvu = yA;                                // reuse (layer-2 y dead)
    bf16u* combu = (bf16u*)gxT;                       // reuse after attention

    hipMemsetAsync(d_ws, 0, 4096, stream);            // zero flags

    embed_ctx_kernel<<<2048, 128, 0, stream>>>(x, context, emb, ctx_W, ctx_b, inp);

    const size_t HS_OFF = (size_t)32768 * 100;
    for (int l = 0; l < 4; ++l) {
        const int K = l ? 384 : 256;
        const float* Wl = l ? (Wih_rest + (size_t)(l - 1) * 1536 * 384) : Wih0;
        const bf16u* Ain = (l == 0) ? inp : ((l == 1 || l == 3) ? yA : yB);
        bf16u* yl = (l & 1) ? yB : yA;
        for (int c = 0; c < 8; ++c) {
            gemm_kernel<<<dim3(24, 64), 256, 0, stream>>>(
                Ain + (size_t)c * 4096 * K, nullptr, K, Wl,
                bih + l * 1536, bhh + l * 1536, gxT, 4096, 1536, K, 0, 4096);
            lstm_chunk_kernel<<<24, 256, 0, stream>>>(
                gxT, Whh + (size_t)l * 1536 * 384,
                h_in + l * 12288, c_in + l * 12288,
                yl, hbuf, cbuf, flags,
                (l * 8 + c) * 130, c * 128,
                c == 0, c == 7,
                out + HS_OFF + l * 12288, out + HS_OFF + 49152 + l * 12288);
        }
    }
    // keys = y3 @ Wa^T  (yB -> gxT region, bf16)
    gemm_kernel<<<dim3(6, 512), 256, 0, stream>>>(
        yB, nullptr, 384, Wa, nullptr, nullptr, keysu, 32768, 384, 384, 1, 0);
    // ctx_vec (flash attention)  (yB, keys -> yA region)
    attn_kernel<<<dim3(32, 32), 256, 0, stream>>>(yB, keysu, ctxvu);
    // combined = tanh([y3, ctx] @ comb_W^T + b)  (-> gxT region, bf16)
    gemm_kernel<<<dim3(6, 512), 256, 0, stream>>>(
        yB, ctxvu, 384, comb_W, comb_b, nullptr, combu, 32768, 384, 768, 2, 0);
    // logits = combined @ fc_W^T + fc_b  (-> d_out, permuted to [b][t][100])
    gemm_kernel<<<dim3(2, 512), 256, 0, stream>>>(
        combu, nullptr, 384, fc_W, fc_b, nullptr, out, 32768, 100, 384, 3, 0);
}

// Round 7
// 36970.203 us; speedup vs baseline: 1.6525x; 1.6525x over previous
//
#include <hip/hip_runtime.h>

typedef unsigned int  uint32;
typedef unsigned long long u64;
typedef unsigned short bf16u;
typedef __attribute__((ext_vector_type(8))) short s8v;    // 8 bf16 (4 VGPRs)
typedef __attribute__((ext_vector_type(4))) float f4v;    // MFMA acc

__device__ __forceinline__ float fast_tanh(float x) {
    x = fminf(9.f, fmaxf(-9.f, x));
    float e = __expf(2.f * x);
    return (e - 1.f) / (e + 1.f);
}
__device__ __forceinline__ float sigmoidf(float x) {
    return 1.f / (1.f + __expf(-x));
}
__device__ __forceinline__ bf16u f2bf(float f) {
    uint32 u = __float_as_uint(f);
    u += 0x7fffu + ((u >> 16) & 1u);
    return (bf16u)(u >> 16);
}
__device__ __forceinline__ float bf2f(bf16u u) {
    return __uint_as_float(((uint32)u) << 16);
}
__device__ __forceinline__ uint32 pack2bf(float lo, float hi) {
    return (uint32)f2bf(lo) | ((uint32)f2bf(hi) << 16);
}
__device__ __forceinline__ float bflo(uint32 p) { return __uint_as_float(p << 16); }
__device__ __forceinline__ float bfhi(uint32 p) { return __uint_as_float(p & 0xffff0000u); }

// ---------------------------------------------------------------------------
// Embedding + context projection -> inp [rt=t*32+b][256] bf16 (emb || ctx)
// ---------------------------------------------------------------------------
__global__ void __launch_bounds__(128) embed_ctx_kernel(
    const int* __restrict__ x, const float* __restrict__ ctx,
    const float* __restrict__ emb, const float* __restrict__ ctxW,
    const float* __restrict__ ctxb, bf16u* __restrict__ inp)
{
    const int r0 = blockIdx.x * 16;
    const int tid = threadIdx.x;
    __shared__ float cs[16][301];
    __shared__ int xs[16];
    for (int i = tid; i < 16 * 300; i += 128) {
        int row = i / 300, k = i - row * 300;
        int rt = r0 + row, b = rt & 31, t = rt >> 5;
        cs[row][k] = ctx[((size_t)b * 1024 + t) * 300 + k];
    }
    if (tid < 16) {
        int rt = r0 + tid;
        xs[tid] = x[(rt & 31) * 1024 + (rt >> 5)];
    }
    __syncthreads();
    float acc[16];
    #pragma unroll
    for (int row = 0; row < 16; ++row) acc[row] = 0.f;
    for (int k = 0; k < 300; ++k) {
        float w = ctxW[tid * 300 + k];
        #pragma unroll
        for (int row = 0; row < 16; ++row) acc[row] = fmaf(w, cs[row][k], acc[row]);
    }
    float bb = ctxb[tid];
    for (int row = 0; row < 16; ++row) {
        size_t base = (size_t)(r0 + row) * 256;
        inp[base + tid]       = f2bf(emb[xs[row] * 128 + tid]);
        inp[base + 128 + tid] = f2bf(acc[row] + bb);
    }
}

// ---------------------------------------------------------------------------
// MFMA GEMM: C[M,N] = A[M,K](bf16) @ W[N,K]^T(f32, split hi/lo bf16)
// A split at K0 between A0/A1 (both bf16, row strides K0 / K-K0).
// mode 0: f32 out TRANSPOSED -> Cout[col*ldc + row]  (for gxT)
// mode 1: bf16 out; mode 2: bf16+tanh; mode 3: f32 out, row rt->(b*1024+t).
// BM=BN=64, BK=32; 4 waves, each a 32x32 quadrant via 2x2 16x16x32 MFMAs.
// ---------------------------------------------------------------------------
__global__ void __launch_bounds__(256) gemm_kernel(
    const bf16u* __restrict__ A0, const bf16u* __restrict__ A1, int K0,
    const float* __restrict__ W, const float* __restrict__ bias1,
    const float* __restrict__ bias2, void* __restrict__ Cout,
    int M, int N, int K, int mode, int ldc)
{
    __shared__ bf16u As[64][40];     // row stride 40 bf16 = 80 B (2-way max)
    __shared__ bf16u Whi[64][40];
    __shared__ bf16u Wlo[64][40];
    const int tid = threadIdx.x;
    const int bn = blockIdx.x * 64, bm = blockIdx.y * 64;
    const int wave = tid >> 6, lane = tid & 63;
    const int wm = wave >> 1, wn = wave & 1;
    const int ncol = lane & 15, quad = lane >> 4;
    const int lr = tid >> 2, lk = (tid & 3) * 8;   // loader: row, k-offset

    f4v acc[2][2];
    #pragma unroll
    for (int i = 0; i < 2; ++i)
        #pragma unroll
        for (int j = 0; j < 2; ++j) acc[i][j] = (f4v){0.f, 0.f, 0.f, 0.f};

    const int wrow = bn + lr;
    for (int k0 = 0; k0 < K; k0 += 32) {
        const bf16u* Ab; int kb, lda;
        if (k0 < K0) { Ab = A0; kb = k0; lda = K0; }
        else         { Ab = A1; kb = k0 - K0; lda = K - K0; }
        uint4 av = *(const uint4*)(Ab + (size_t)(bm + lr) * lda + kb + lk);
        float4 w0 = make_float4(0.f, 0.f, 0.f, 0.f), w1 = w0;
        if (wrow < N) {
            const float* wp = W + (size_t)wrow * K + k0 + lk;
            w0 = *(const float4*)wp;
            w1 = *(const float4*)(wp + 4);
        }
        __syncthreads();
        *(uint4*)&As[lr][lk] = av;
        {
            bf16u h[8], l[8];
            float wf[8] = {w0.x, w0.y, w0.z, w0.w, w1.x, w1.y, w1.z, w1.w};
            #pragma unroll
            for (int j = 0; j < 8; ++j) {
                h[j] = f2bf(wf[j]);
                l[j] = f2bf(wf[j] - bf2f(h[j]));
            }
            #pragma unroll
            for (int j = 0; j < 8; ++j) Whi[lr][lk + j] = h[j];
            #pragma unroll
            for (int j = 0; j < 8; ++j) Wlo[lr][lk + j] = l[j];
        }
        __syncthreads();
        s8v aF[2], bH[2], bL[2];
        #pragma unroll
        for (int mt = 0; mt < 2; ++mt)
            aF[mt] = *(const s8v*)&As[wm * 32 + mt * 16 + ncol][quad * 8];
        #pragma unroll
        for (int nt = 0; nt < 2; ++nt) {
            bH[nt] = *(const s8v*)&Whi[wn * 32 + nt * 16 + ncol][quad * 8];
            bL[nt] = *(const s8v*)&Wlo[wn * 32 + nt * 16 + ncol][quad * 8];
        }
        #pragma unroll
        for (int mt = 0; mt < 2; ++mt)
            #pragma unroll
            for (int nt = 0; nt < 2; ++nt) {
                acc[mt][nt] = __builtin_amdgcn_mfma_f32_16x16x32_bf16(
                    aF[mt], bH[nt], acc[mt][nt], 0, 0, 0);
                acc[mt][nt] = __builtin_amdgcn_mfma_f32_16x16x32_bf16(
                    aF[mt], bL[nt], acc[mt][nt], 0, 0, 0);
            }
    }

    #pragma unroll
    for (int nt = 0; nt < 2; ++nt) {
        const int col = bn + wn * 32 + nt * 16 + ncol;
        if (col >= N) continue;
        float bb = 0.f;
        if (bias1) bb += bias1[col];
        if (bias2) bb += bias2[col];
        #pragma unroll
        for (int mt = 0; mt < 2; ++mt) {
            const int rowb = bm + wm * 32 + mt * 16 + quad * 4;
            if (mode == 0) {
                float4 v;
                v.x = acc[mt][nt][0] + bb;
                v.y = acc[mt][nt][1] + bb;
                v.z = acc[mt][nt][2] + bb;
                v.w = acc[mt][nt][3] + bb;
                *(float4*)((float*)Cout + (size_t)col * ldc + rowb) = v;
            } else if (mode == 3) {
                #pragma unroll
                for (int r = 0; r < 4; ++r) {
                    int row = rowb + r;
                    int b = row & 31, t = row >> 5;
                    ((float*)Cout)[((size_t)b * 1024 + t) * (size_t)N + col] =
                        acc[mt][nt][r] + bb;
                }
            } else {
                #pragma unroll
                for (int r = 0; r < 4; ++r) {
                    float v = acc[mt][nt][r] + bb;
                    if (mode == 2) v = fast_tanh(v);
                    ((bf16u*)Cout)[(size_t)(rowb + r) * N + col] = f2bf(v);
                }
            }
        }
    }
}

// ---------------------------------------------------------------------------
// Flag barrier, 48 blocks, one flag per 128-B line. Lanes 0..47 poll 48
// distinct lines in parallel with s_sleep backoff. Monotonic rounds.
// __syncthreads() before the store drains vmcnt(0) -> prior agent-scope
// h-stores are at the coherence point before the flag becomes visible.
// ---------------------------------------------------------------------------
__device__ __forceinline__ void flag_barrier(uint32* flags, uint32 r,
                                             int tid, int bid) {
    __syncthreads();
    if (tid == 0)
        __hip_atomic_store(&flags[bid * 32], r, __ATOMIC_RELAXED, __HIP_MEMORY_SCOPE_AGENT);
    if (tid < 48) {
        while (__hip_atomic_load(&flags[tid * 32], __ATOMIC_RELAXED,
                                 __HIP_MEMORY_SCOPE_AGENT) < r)
            __builtin_amdgcn_s_sleep(1);
    }
    __syncthreads();
}

// ---------------------------------------------------------------------------
// LSTM, one 128-step chunk. 48 blocks x 256 threads. Block owns 8 hidden
// dims (32 gate rows); Whh slice in registers as hi/lo bf16 B-frags.
// h lives in hbuf[parity][plane hi/lo][32 b][196 u32] (padded stride 196
// == LDS stage stride -> straight u64 copy, and 196%32=4 -> only 2-way
// bank alias on ds_read_b128 fragments, which is free). Per step: stage
// the 49 KB parity buffer into LDS with ~25 independent agent-scope u64
// loads per thread (one latency, not 96 serialized), MFMA from LDS, cell
// update, h store, flag barrier.
// ---------------------------------------------------------------------------
#define HPAR 12544          // u32 per parity (2 planes * 32 * 196)
#define HPLANE 6272         // u32 per plane (32*196)
__global__ void __launch_bounds__(256, 1) lstm_chunk_kernel(
    const float* __restrict__ gxT,   // [1536][4096] fp32 (chunk, col=tl*32+b)
    const float* __restrict__ Whh,   // [1536][384] fp32
    const float* __restrict__ h0, const float* __restrict__ c0,
    bf16u* __restrict__ y,           // [t*32+b][384] bf16
    uint32* __restrict__ hbuf,       // [2][2][32][196] u32
    float* __restrict__ cbuf, uint32* __restrict__ flags,
    int roundBase, int t0, int is_first, int is_last,
    float* __restrict__ hs_out, float* __restrict__ cs_out)
{
    const int tid = threadIdx.x, bid = blockIdx.x;   // 48 blocks
    const int j0 = bid * 8;
    const int wave = tid >> 6, lane = tid & 63;
    const int ntile = wave & 1, mtile = wave >> 1;
    const int ncol = lane & 15, quad = lane >> 4;
    const int n = ntile * 16 + ncol;            // local gate-row 0..31
    const int wrow = (n >> 3) * 384 + j0 + (n & 7);
    const int Mrow = mtile * 16 + ncol;         // batch row for A-frag

    __shared__ u64 hstage[HPAR / 2];            // 49 KB staged h (both planes)
    __shared__ float gates_s[32][33];

    // ---- B fragments: Whh rows split hi/lo bf16 (once per launch) ----
    s8v Bhi[12], Blo[12];
    #pragma unroll
    for (int kt = 0; kt < 12; ++kt) {
        const float* wp = Whh + (size_t)wrow * 384 + kt * 32 + quad * 8;
        s8v hi, lo;
        #pragma unroll
        for (int j = 0; j < 8; ++j) {
            float w = wp[j];
            bf16u wh = f2bf(w);
            bf16u wl = f2bf(w - bf2f(wh));
            hi[j] = (short)wh; lo[j] = (short)wl;
        }
        Bhi[kt] = hi; Blo[kt] = lo;
    }

    // update mapping: tid<128 owns (batch ub, j-pair jg0=j0+2*jp)
    const int ub = tid & 31, jp = tid >> 5;     // jp 0..3 valid for tid<128
    const int jg0 = j0 + 2 * jp;
    const int wcol = bid * 4 + jp;              // u32 column in planes
    float c0r = 0.f, c1r = 0.f, h0l = 0.f, h1l = 0.f;

    if (tid < 128) {
        if (is_first) {
            float ha = h0[ub * 384 + jg0], hb = h0[ub * 384 + jg0 + 1];
            bf16u ha_h = f2bf(ha); bf16u ha_l = f2bf(ha - bf2f(ha_h));
            bf16u hb_h = f2bf(hb); bf16u hb_l = f2bf(hb - bf2f(hb_h));
            __hip_atomic_store(&hbuf[ub * 196 + wcol],
                               (uint32)ha_h | ((uint32)hb_h << 16),
                               __ATOMIC_RELAXED, __HIP_MEMORY_SCOPE_AGENT);
            __hip_atomic_store(&hbuf[HPLANE + ub * 196 + wcol],
                               (uint32)ha_l | ((uint32)hb_l << 16),
                               __ATOMIC_RELAXED, __HIP_MEMORY_SCOPE_AGENT);
            c0r = c0[ub * 384 + jg0];
            c1r = c0[ub * 384 + jg0 + 1];
        } else {
            c0r = cbuf[ub * 384 + jg0];
            c1r = cbuf[ub * 384 + jg0 + 1];
        }
    }
    flag_barrier(flags, (uint32)(roundBase + 1), tid, bid);

    const uint32* hs32 = (const uint32*)hstage;
    for (int tl = 0; tl < 128; ++tl) {
        const int t = t0 + tl;
        const u64* hR = (const u64*)(hbuf + (t & 1) * HPAR);
        uint32* hW = hbuf + ((t + 1) & 1) * HPAR;

        // ---- stage h parity buffer -> LDS (independent coherent loads) ----
        #pragma unroll
        for (int k = 0; k < 24; ++k) {
            int idx = k * 256 + tid;
            hstage[idx] = __hip_atomic_load(hR + idx, __ATOMIC_RELAXED,
                                            __HIP_MEMORY_SCOPE_AGENT);
        }
        if (tid < HPAR / 2 - 6144)
            hstage[6144 + tid] = __hip_atomic_load(hR + 6144 + tid,
                                                   __ATOMIC_RELAXED,
                                                   __HIP_MEMORY_SCOPE_AGENT);

        // gx prefetch for the update role (plain loads, L2-hot, coalesced)
        float gxv[8];
        if (tid < 128) {
            #pragma unroll
            for (int g = 0; g < 4; ++g) {
                gxv[g]     = gxT[(size_t)(g * 384 + jg0) * 4096 + tl * 32 + ub];
                gxv[4 + g] = gxT[(size_t)(g * 384 + jg0 + 1) * 4096 + tl * 32 + ub];
            }
        }
        __syncthreads();     // staging complete

        // ---- MFMA: gates[32 b x 32 rows] = h x Whh^T (hi/lo split) ----
        f4v aHH = {0.f, 0.f, 0.f, 0.f};
        f4v aLH = {0.f, 0.f, 0.f, 0.f};
        f4v aHL = {0.f, 0.f, 0.f, 0.f};
        #pragma unroll
        for (int kt = 0; kt < 12; ++kt) {
            const int cofs = kt * 16 + quad * 4;
            s8v Ah = *(const s8v*)&hs32[Mrow * 196 + cofs];
            s8v Al = *(const s8v*)&hs32[HPLANE + Mrow * 196 + cofs];
            aHH = __builtin_amdgcn_mfma_f32_16x16x32_bf16(Ah, Bhi[kt], aHH, 0, 0, 0);
            aLH = __builtin_amdgcn_mfma_f32_16x16x32_bf16(Al, Bhi[kt], aLH, 0, 0, 0);
            aHL = __builtin_amdgcn_mfma_f32_16x16x32_bf16(Ah, Blo[kt], aHL, 0, 0, 0);
        }
        #pragma unroll
        for (int r = 0; r < 4; ++r)
            gates_s[n][mtile * 16 + quad * 4 + r] = aHH[r] + aLH[r] + aHL[r];
        __syncthreads();

        // ---- cell update: tid<128, two hidden dims each ----
        if (tid < 128) {
            const int jj0 = 2 * jp, jj1 = 2 * jp + 1;
            float pi0 = gates_s[jj0][ub]      + gxv[0];
            float pf0 = gates_s[8 + jj0][ub]  + gxv[1];
            float pg0 = gates_s[16 + jj0][ub] + gxv[2];
            float po0 = gates_s[24 + jj0][ub] + gxv[3];
            float pi1 = gates_s[jj1][ub]      + gxv[4];
            float pf1 = gates_s[8 + jj1][ub]  + gxv[5];
            float pg1 = gates_s[16 + jj1][ub] + gxv[6];
            float po1 = gates_s[24 + jj1][ub] + gxv[7];
            c0r = sigmoidf(pf0) * c0r + sigmoidf(pi0) * fast_tanh(pg0);
            c1r = sigmoidf(pf1) * c1r + sigmoidf(pi1) * fast_tanh(pg1);
            float hv0 = sigmoidf(po0) * fast_tanh(c0r);
            float hv1 = sigmoidf(po1) * fast_tanh(c1r);
            h0l = hv0; h1l = hv1;
            bf16u h0h = f2bf(hv0); bf16u h0lo = f2bf(hv0 - bf2f(h0h));
            bf16u h1h = f2bf(hv1); bf16u h1lo = f2bf(hv1 - bf2f(h1h));
            __hip_atomic_store(&hW[ub * 196 + wcol],
                               (uint32)h0h | ((uint32)h1h << 16),
                               __ATOMIC_RELAXED, __HIP_MEMORY_SCOPE_AGENT);
            __hip_atomic_store(&hW[HPLANE + ub * 196 + wcol],
                               (uint32)h0lo | ((uint32)h1lo << 16),
                               __ATOMIC_RELAXED, __HIP_MEMORY_SCOPE_AGENT);
            *(uint32*)(y + ((size_t)t * 32 + ub) * 384 + jg0) =
                (uint32)h0h | ((uint32)h1h << 16);
        }
        flag_barrier(flags, (uint32)(roundBase + tl + 2), tid, bid);
    }

    if (tid < 128) {
        cbuf[ub * 384 + jg0]     = c0r;
        cbuf[ub * 384 + jg0 + 1] = c1r;
        if (is_last) {
            hs_out[ub * 384 + jg0]     = h0l;
            hs_out[ub * 384 + jg0 + 1] = h1l;
            cs_out[ub * 384 + jg0]     = c0r;
            cs_out[ub * 384 + jg0 + 1] = c1r;
        }
    }
}

// ---------------------------------------------------------------------------
// Causal flash attention, bf16 in/out (unchanged from passing round).
// ---------------------------------------------------------------------------
__global__ void __launch_bounds__(256) attn_kernel(
    const bf16u* __restrict__ outy, const bf16u* __restrict__ keys,
    bf16u* __restrict__ ctxv)
{
    const int b = blockIdx.y;
    const int q0 = blockIdx.x * 32;
    const int tid = threadIdx.x;
    __shared__ uint32 Qs[32][194];
    __shared__ uint32 Ks[16][194];
    __shared__ uint32 Vs[16][192];
    __shared__ float Ss[32][16];
    __shared__ float m_s[32], l_s[32], alpha_s[32];

    for (int i = tid; i < 32 * 192; i += 256) {
        int q = i / 192, dp = i - q * 192;
        Qs[q][dp] = ((const uint32*)(outy + ((size_t)(q0 + q) * 32 + b) * 384))[dp];
    }
    if (tid < 32) { m_s[tid] = -3e38f; l_s[tid] = 0.f; }

    const int qo = tid >> 3, dg = tid & 7;
    float O[48];
    #pragma unroll
    for (int d = 0; d < 48; ++d) O[d] = 0.f;

    const int nkt = (q0 + 32) >> 4;
    for (int kt = 0; kt < nkt; ++kt) {
        const int k0 = kt * 16;
        __syncthreads();
        for (int i = tid; i < 16 * 192; i += 256) {
            int kk = i / 192, dp = i - kk * 192;
            size_t rt = (size_t)(k0 + kk) * 32 + b;
            Ks[kk][dp] = ((const uint32*)(keys + rt * 384))[dp];
            Vs[kk][dp] = ((const uint32*)(outy + rt * 384))[dp];
        }
        __syncthreads();
        #pragma unroll
        for (int pp = 0; pp < 2; ++pp) {
            int p = tid + pp * 256;
            int q = p >> 4, k = p & 15;
            const uint32* qrow = Qs[q];
            const uint32* krow = Ks[k];
            float acc = 0.f;
            for (int dp = 0; dp < 192; ++dp) {
                uint32 qa = qrow[dp], ka = krow[dp];
                acc = fmaf(bflo(qa), bflo(ka), acc);
                acc = fmaf(bfhi(qa), bfhi(ka), acc);
            }
            acc *= 0.051031036307982884f;    // 1/sqrt(384)
            Ss[q][k] = ((k0 + k) <= (q0 + q)) ? acc : -1e30f;
        }
        __syncthreads();
        if (tid < 32) {
            int q = tid;
            float mt = m_s[q];
            #pragma unroll
            for (int k = 0; k < 16; ++k) mt = fmaxf(mt, Ss[q][k]);
            float alpha = __expf(m_s[q] - mt);
            float l = l_s[q] * alpha;
            #pragma unroll
            for (int k = 0; k < 16; ++k) {
                float pv = __expf(Ss[q][k] - mt);
                Ss[q][k] = pv;
                l += pv;
            }
            m_s[q] = mt; l_s[q] = l; alpha_s[q] = alpha;
        }
        __syncthreads();
        {
            float al = alpha_s[qo];
            #pragma unroll
            for (int d = 0; d < 48; ++d) O[d] *= al;
            for (int k = 0; k < 16; ++k) {
                float pv = Ss[qo][k];
                const uint32* vrow = Vs[k] + dg * 24;
                #pragma unroll
                for (int dp = 0; dp < 24; ++dp) {
                    uint32 va = vrow[dp];
                    O[2 * dp]     = fmaf(pv, bflo(va), O[2 * dp]);
                    O[2 * dp + 1] = fmaf(pv, bfhi(va), O[2 * dp + 1]);
                }
            }
        }
    }
    float inv = 1.f / l_s[qo];
    uint32* dst = (uint32*)(ctxv + ((size_t)(q0 + qo) * 32 + b) * 384) + dg * 24;
    #pragma unroll
    for (int dp = 0; dp < 24; ++dp)
        dst[dp] = pack2bf(O[2 * dp] * inv, O[2 * dp + 1] * inv);
}

// ---------------------------------------------------------------------------
extern "C" void kernel_launch(void* const* d_in, const int* in_sizes, int n_in,
                              void* d_out, int out_size, void* d_ws, size_t ws_size,
                              hipStream_t stream) {
    (void)in_sizes; (void)n_in; (void)out_size; (void)ws_size;
    const int*   x        = (const int*)d_in[0];
    const float* context  = (const float*)d_in[1];
    const float* h_in     = (const float*)d_in[2];
    const float* c_in     = (const float*)d_in[3];
    const float* emb      = (const float*)d_in[4];
    const float* ctx_W    = (const float*)d_in[5];
    const float* ctx_b    = (const float*)d_in[6];
    const float* Wih0     = (const float*)d_in[7];
    const float* Wih_rest = (const float*)d_in[8];
    const float* Whh      = (const float*)d_in[9];
    const float* bih      = (const float*)d_in[10];
    const float* bhh      = (const float*)d_in[11];
    const float* Wa       = (const float*)d_in[12];
    const float* comb_W   = (const float*)d_in[13];
    const float* comb_b   = (const float*)d_in[14];
    const float* fc_W     = (const float*)d_in[15];
    const float* fc_b     = (const float*)d_in[16];
    float* out = (float*)d_out;

    // ---- workspace layout ----
    char* wsb = (char*)d_ws;
    uint32* flags = (uint32*)(wsb + 0);               //   8 KB (48 x 128-B lines)
    uint32* hbuf  = (uint32*)(wsb + 8192);            // 100 KB [2][2][32][196]
    float*  cbuf  = (float*)(wsb + 108544);           //  48 KB [32][384]
    bf16u*  inp   = (bf16u*)(wsb + 157696);           //  16.78 MB [32768,256]
    bf16u*  yA    = (bf16u*)(wsb + 16934912ull);      //  25.17 MB [32768,384]
    bf16u*  yB    = (bf16u*)(wsb + 42100736ull);      //  25.17 MB [32768,384]
    float*  gxT   = (float*)(wsb + 67266560ull);      //  25.17 MB [1536,4096]
    bf16u* keysu = (bf16u*)gxT;                       // reuse after LSTM stack
    bf16u* ctxvu = yA;                                // reuse (layer-2 y dead)
    bf16u* combu = (bf16u*)gxT;                       // reuse after attention

    hipMemsetAsync(d_ws, 0, 8192, stream);            // zero flags

    embed_ctx_kernel<<<2048, 128, 0, stream>>>(x, context, emb, ctx_W, ctx_b, inp);

    const size_t HS_OFF = (size_t)32768 * 100;
    for (int l = 0; l < 4; ++l) {
        const int K = l ? 384 : 256;
        const float* Wl = l ? (Wih_rest + (size_t)(l - 1) * 1536 * 384) : Wih0;
        const bf16u* Ain = (l == 0) ? inp : ((l == 1 || l == 3) ? yA : yB);
        bf16u* yl = (l & 1) ? yB : yA;
        for (int c = 0; c < 8; ++c) {
            gemm_kernel<<<dim3(24, 64), 256, 0, stream>>>(
                Ain + (size_t)c * 4096 * K, nullptr, K, Wl,
                bih + l * 1536, bhh + l * 1536, gxT, 4096, 1536, K, 0, 4096);
            lstm_chunk_kernel<<<48, 256, 0, stream>>>(
                gxT, Whh + (size_t)l * 1536 * 384,
                h_in + l * 12288, c_in + l * 12288,
                yl, hbuf, cbuf, flags,
                (l * 8 + c) * 130, c * 128,
                c == 0, c == 7,
                out + HS_OFF + l * 12288, out + HS_OFF + 49152 + l * 12288);
        }
    }
    // keys = y3 @ Wa^T  (yB -> gxT region, bf16)
    gemm_kernel<<<dim3(6, 512), 256, 0, stream>>>(
        yB, nullptr, 384, Wa, nullptr, nullptr, keysu, 32768, 384, 384, 1, 0);
    // ctx_vec (flash attention)  (yB, keys -> yA region)
    attn_kernel<<<dim3(32, 32), 256, 0, stream>>>(yB, keysu, ctxvu);
    // combined = tanh([y3, ctx] @ comb_W^T + b)  (-> gxT region, bf16)
    gemm_kernel<<<dim3(6, 512), 256, 0, stream>>>(
        yB, ctxvu, 384, comb_W, comb_b, nullptr, combu, 32768, 384, 768, 2, 0);
    // logits = combined @ fc_W^T + fc_b  (-> d_out, permuted to [b][t][100])
    gemm_kernel<<<dim3(2, 512), 256, 0, stream>>>(
        combu, nullptr, 384, fc_W, fc_b, nullptr, out, 32768, 100, 384, 3, 0);
}

// Round 8
// 14876.913 us; speedup vs baseline: 4.1067x; 2.4851x over previous
//
#include <hip/hip_runtime.h>

typedef unsigned int  uint32;
typedef unsigned long long u64;
typedef unsigned short bf16u;
typedef __attribute__((ext_vector_type(8))) short s8v;    // 8 bf16 (4 VGPRs)
typedef __attribute__((ext_vector_type(4))) float f4v;    // MFMA acc

#define HPLANE 6272          // u32 per plane (32*196)
#define HPAR   12544         // u32 per parity (2 planes)
#define HB     25088         // u32 per layer hbuf (2 parities)

__device__ __forceinline__ float fast_tanh(float x) {
    x = fminf(9.f, fmaxf(-9.f, x));
    float e = __expf(2.f * x);
    return (e - 1.f) / (e + 1.f);
}
__device__ __forceinline__ float sigmoidf(float x) {
    return 1.f / (1.f + __expf(-x));
}
__device__ __forceinline__ bf16u f2bf(float f) {
    uint32 u = __float_as_uint(f);
    u += 0x7fffu + ((u >> 16) & 1u);
    return (bf16u)(u >> 16);
}
__device__ __forceinline__ float bf2f(bf16u u) {
    return __uint_as_float(((uint32)u) << 16);
}
__device__ __forceinline__ uint32 pack2bf(float lo, float hi) {
    return (uint32)f2bf(lo) | ((uint32)f2bf(hi) << 16);
}
__device__ __forceinline__ float bflo(uint32 p) { return __uint_as_float(p << 16); }
__device__ __forceinline__ float bfhi(uint32 p) { return __uint_as_float(p & 0xffff0000u); }

// ---------------------------------------------------------------------------
// Embedding + context projection -> inp [rt=t*32+b][256] bf16 (emb || ctx)
// ---------------------------------------------------------------------------
__global__ void __launch_bounds__(128) embed_ctx_kernel(
    const int* __restrict__ x, const float* __restrict__ ctx,
    const float* __restrict__ emb, const float* __restrict__ ctxW,
    const float* __restrict__ ctxb, bf16u* __restrict__ inp)
{
    const int r0 = blockIdx.x * 16;
    const int tid = threadIdx.x;
    __shared__ float cs[16][301];
    __shared__ int xs[16];
    for (int i = tid; i < 16 * 300; i += 128) {
        int row = i / 300, k = i - row * 300;
        int rt = r0 + row, b = rt & 31, t = rt >> 5;
        cs[row][k] = ctx[((size_t)b * 1024 + t) * 300 + k];
    }
    if (tid < 16) {
        int rt = r0 + tid;
        xs[tid] = x[(rt & 31) * 1024 + (rt >> 5)];
    }
    __syncthreads();
    float acc[16];
    #pragma unroll
    for (int row = 0; row < 16; ++row) acc[row] = 0.f;
    for (int k = 0; k < 300; ++k) {
        float w = ctxW[tid * 300 + k];
        #pragma unroll
        for (int row = 0; row < 16; ++row) acc[row] = fmaf(w, cs[row][k], acc[row]);
    }
    float bb = ctxb[tid];
    for (int row = 0; row < 16; ++row) {
        size_t base = (size_t)(r0 + row) * 256;
        inp[base + tid]       = f2bf(emb[xs[row] * 128 + tid]);
        inp[base + 128 + tid] = f2bf(acc[row] + bb);
    }
}

// ---------------------------------------------------------------------------
// MFMA GEMM: C[M,N] = A[M,K](bf16) @ W[N,K]^T(f32, split hi/lo bf16)
// A split at K0 between A0/A1. mode 1: bf16 out; 2: bf16+tanh;
// 3: f32 out, row rt->(b*1024+t) (logits). BM=BN=64, BK=32.
// ---------------------------------------------------------------------------
__global__ void __launch_bounds__(256) gemm_kernel(
    const bf16u* __restrict__ A0, const bf16u* __restrict__ A1, int K0,
    const float* __restrict__ W, const float* __restrict__ bias1,
    void* __restrict__ Cout, int M, int N, int K, int mode)
{
    __shared__ bf16u As[64][40];
    __shared__ bf16u Whi[64][40];
    __shared__ bf16u Wlo[64][40];
    const int tid = threadIdx.x;
    const int bn = blockIdx.x * 64, bm = blockIdx.y * 64;
    const int wave = tid >> 6, lane = tid & 63;
    const int wm = wave >> 1, wn = wave & 1;
    const int ncol = lane & 15, quad = lane >> 4;
    const int lr = tid >> 2, lk = (tid & 3) * 8;

    f4v acc[2][2];
    #pragma unroll
    for (int i = 0; i < 2; ++i)
        #pragma unroll
        for (int j = 0; j < 2; ++j) acc[i][j] = (f4v){0.f, 0.f, 0.f, 0.f};

    const int wrow = bn + lr;
    for (int k0 = 0; k0 < K; k0 += 32) {
        const bf16u* Ab; int kb, lda;
        if (k0 < K0) { Ab = A0; kb = k0; lda = K0; }
        else         { Ab = A1; kb = k0 - K0; lda = K - K0; }
        uint4 av = *(const uint4*)(Ab + (size_t)(bm + lr) * lda + kb + lk);
        float4 w0 = make_float4(0.f, 0.f, 0.f, 0.f), w1 = w0;
        if (wrow < N) {
            const float* wp = W + (size_t)wrow * K + k0 + lk;
            w0 = *(const float4*)wp;
            w1 = *(const float4*)(wp + 4);
        }
        __syncthreads();
        *(uint4*)&As[lr][lk] = av;
        {
            bf16u h[8], l[8];
            float wf[8] = {w0.x, w0.y, w0.z, w0.w, w1.x, w1.y, w1.z, w1.w};
            #pragma unroll
            for (int j = 0; j < 8; ++j) {
                h[j] = f2bf(wf[j]);
                l[j] = f2bf(wf[j] - bf2f(h[j]));
            }
            #pragma unroll
            for (int j = 0; j < 8; ++j) Whi[lr][lk + j] = h[j];
            #pragma unroll
            for (int j = 0; j < 8; ++j) Wlo[lr][lk + j] = l[j];
        }
        __syncthreads();
        s8v aF[2], bH[2], bL[2];
        #pragma unroll
        for (int mt = 0; mt < 2; ++mt)
            aF[mt] = *(const s8v*)&As[wm * 32 + mt * 16 + ncol][quad * 8];
        #pragma unroll
        for (int nt = 0; nt < 2; ++nt) {
            bH[nt] = *(const s8v*)&Whi[wn * 32 + nt * 16 + ncol][quad * 8];
            bL[nt] = *(const s8v*)&Wlo[wn * 32 + nt * 16 + ncol][quad * 8];
        }
        #pragma unroll
        for (int mt = 0; mt < 2; ++mt)
            #pragma unroll
            for (int nt = 0; nt < 2; ++nt) {
                acc[mt][nt] = __builtin_amdgcn_mfma_f32_16x16x32_bf16(
                    aF[mt], bH[nt], acc[mt][nt], 0, 0, 0);
                acc[mt][nt] = __builtin_amdgcn_mfma_f32_16x16x32_bf16(
                    aF[mt], bL[nt], acc[mt][nt], 0, 0, 0);
            }
    }

    #pragma unroll
    for (int nt = 0; nt < 2; ++nt) {
        const int col = bn + wn * 32 + nt * 16 + ncol;
        if (col >= N) continue;
        float bb = bias1 ? bias1[col] : 0.f;
        #pragma unroll
        for (int mt = 0; mt < 2; ++mt) {
            const int rowb = bm + wm * 32 + mt * 16 + quad * 4;
            if (mode == 3) {
                #pragma unroll
                for (int r = 0; r < 4; ++r) {
                    int row = rowb + r;
                    int b = row & 31, t = row >> 5;
                    ((float*)Cout)[((size_t)b * 1024 + t) * (size_t)N + col] =
                        acc[mt][nt][r] + bb;
                }
            } else {
                #pragma unroll
                for (int r = 0; r < 4; ++r) {
                    float v = acc[mt][nt][r] + bb;
                    if (mode == 2) v = fast_tanh(v);
                    ((bf16u*)Cout)[(size_t)(rowb + r) * N + col] = f2bf(v);
                }
            }
        }
    }
}

// ---------------------------------------------------------------------------
// Flag barrier, 192 blocks, one flag per 128-B line. Lanes 0..191 poll.
// __syncthreads() before the store drains vmcnt(0) -> prior agent-scope
// h-stores are at the coherence point before the flag becomes visible.
// ---------------------------------------------------------------------------
__device__ __forceinline__ void flag_barrier(uint32* flags, uint32 r,
                                             int tid, int bid) {
    __syncthreads();
    if (tid == 0)
        __hip_atomic_store(&flags[bid * 32], r, __ATOMIC_RELAXED, __HIP_MEMORY_SCOPE_AGENT);
    if (tid < 192) {
        while (__hip_atomic_load(&flags[tid * 32], __ATOMIC_RELAXED,
                                 __HIP_MEMORY_SCOPE_AGENT) < r)
            __builtin_amdgcn_s_sleep(1);
    }
    __syncthreads();
}

// ---------------------------------------------------------------------------
// Layer-wavefront LSTM: ALL 4 layers x 1024 steps in ONE launch.
// 192 blocks = 4 layers x 48 blocks x 8 hidden dims. Round r: layer l
// processes t = r - l. Input y_{l-1,t} is layer l-1's h broadcast (parity
// (t+1)&1) -- the hand-off is free. x-path (Wih @ y) fused in-kernel from
// an LDS-resident hi/lo Wih slice; layer 0 reads inp (bf16) directly.
// 1027 barrier rounds instead of 4096.
// ---------------------------------------------------------------------------
__global__ void __launch_bounds__(256, 1) lstm_wave_kernel(
    const bf16u* __restrict__ inp,   // [t*32+b][256] bf16
    const float* __restrict__ Wih0,  // [1536][256]
    const float* __restrict__ WihR,  // [3][1536][384]
    const float* __restrict__ Whh,   // [4][1536][384]
    const float* __restrict__ bih, const float* __restrict__ bhh,
    const float* __restrict__ h_in, const float* __restrict__ c_in,
    bf16u* __restrict__ y3,          // [t*32+b][384] bf16 (layer-3 output)
    uint32* __restrict__ hbuf,       // [4][2][2][32][196] u32
    uint32* __restrict__ flags,
    float* __restrict__ hs_out, float* __restrict__ cs_out)
{
    extern __shared__ char sm[];
    const int tid = threadIdx.x, bid = blockIdx.x;
    const int l = bid / 48, sub = bid - l * 48;
    const int j0 = sub * 8;
    const int wave = tid >> 6, lane = tid & 63;
    const int ntile = wave & 1, mtile = wave >> 1;
    const int ncol = lane & 15, quad = lane >> 4;
    const int n = ntile * 16 + ncol;                 // local gate-row 0..31
    const int gsel = n >> 3, jln = n & 7;
    const int Mrow = mtile * 16 + ncol;

    const int Kx = l ? 384 : 256;
    const int WSTR = l ? 392 : 264;                  // padded bf16 stride
    const int wbytes = 2 * 32 * WSTR * 2;            // Wih planes bytes
    bf16u* wlds  = (bf16u*)sm;
    u64*  hstage = (u64*)(sm + wbytes);
    u64*  ystage = (u64*)(sm + wbytes + 50176);      // or inp stage (l==0)
    float* gates = (float*)(sm + wbytes + 50176 + (l ? 50176 : 16896));
    uint32* hs32 = (uint32*)hstage;
    uint32* ys32 = (uint32*)ystage;
    bf16u*  ist  = (bf16u*)ystage;

    const float* WhhL = Whh + (size_t)l * 1536 * 384;
    const float* WihL = l ? (WihR + (size_t)(l - 1) * 1536 * 384) : Wih0;
    const float* bihL = bih + l * 1536;
    const float* bhhL = bhh + l * 1536;
    uint32* hbL = hbuf + (size_t)l * HB;
    uint32* ybL = l ? (hbuf + (size_t)(l - 1) * HB) : nullptr;

    // ---- Whh B-frags in registers (hi/lo), rows = this block's 32 gates ----
    s8v Bhi[12], Blo[12];
    {
        const int wrow = gsel * 384 + j0 + jln;
        #pragma unroll
        for (int kt = 0; kt < 12; ++kt) {
            const float* wp = WhhL + (size_t)wrow * 384 + kt * 32 + quad * 8;
            s8v hi, lo;
            #pragma unroll
            for (int j = 0; j < 8; ++j) {
                float w = wp[j];
                bf16u wh = f2bf(w);
                bf16u wl = f2bf(w - bf2f(wh));
                hi[j] = (short)wh; lo[j] = (short)wl;
            }
            Bhi[kt] = hi; Blo[kt] = lo;
        }
    }
    // ---- Wih slice into LDS (hi/lo planes) ----
    for (int r2 = 0; r2 < 32; ++r2) {
        int rg = (r2 >> 3) * 384 + j0 + (r2 & 7);
        for (int k = tid; k < Kx; k += 256) {
            float w = WihL[(size_t)rg * Kx + k];
            bf16u wh = f2bf(w);
            wlds[r2 * WSTR + k] = wh;
            wlds[32 * WSTR + r2 * WSTR + k] = f2bf(w - bf2f(wh));
        }
    }

    // update role: tid<128 owns (batch ub, dim pair jg0, jg0+1)
    const int ub = tid & 31, jp = tid >> 5;          // jp 0..3 for tid<128
    const int jg0 = j0 + 2 * jp;
    const int wcol = sub * 4 + jp;
    float c0r = 0.f, c1r = 0.f, h0l = 0.f, h1l = 0.f;
    float bI0 = 0, bF0 = 0, bG0 = 0, bO0 = 0, bI1 = 0, bF1 = 0, bG1 = 0, bO1 = 0;

    if (tid < 128) {
        bI0 = bihL[jg0] + bhhL[jg0];
        bF0 = bihL[384 + jg0] + bhhL[384 + jg0];
        bG0 = bihL[768 + jg0] + bhhL[768 + jg0];
        bO0 = bihL[1152 + jg0] + bhhL[1152 + jg0];
        bI1 = bihL[jg0 + 1] + bhhL[jg0 + 1];
        bF1 = bihL[384 + jg0 + 1] + bhhL[384 + jg0 + 1];
        bG1 = bihL[768 + jg0 + 1] + bhhL[768 + jg0 + 1];
        bO1 = bihL[1152 + jg0 + 1] + bhhL[1152 + jg0 + 1];
        float ha = h_in[(size_t)l * 12288 + ub * 384 + jg0];
        float hb = h_in[(size_t)l * 12288 + ub * 384 + jg0 + 1];
        bf16u ha_h = f2bf(ha); bf16u ha_l = f2bf(ha - bf2f(ha_h));
        bf16u hb_h = f2bf(hb); bf16u hb_l = f2bf(hb - bf2f(hb_h));
        __hip_atomic_store(&hbL[ub * 196 + wcol],
                           (uint32)ha_h | ((uint32)hb_h << 16),
                           __ATOMIC_RELAXED, __HIP_MEMORY_SCOPE_AGENT);
        __hip_atomic_store(&hbL[HPLANE + ub * 196 + wcol],
                           (uint32)ha_l | ((uint32)hb_l << 16),
                           __ATOMIC_RELAXED, __HIP_MEMORY_SCOPE_AGENT);
        c0r = c_in[(size_t)l * 12288 + ub * 384 + jg0];
        c1r = c_in[(size_t)l * 12288 + ub * 384 + jg0 + 1];
    }
    flag_barrier(flags, 1u, tid, bid);

    for (int r = 0; r < 1027; ++r) {
        const int t = r - l;
        if ((unsigned)t < 1024u) {
            const u64* hR = (const u64*)(hbL + (t & 1) * HPAR);
            uint32* hW = hbL + ((t + 1) & 1) * HPAR;

            if (l) {
                const u64* yR = (const u64*)(ybL + ((t + 1) & 1) * HPAR);
                #pragma unroll
                for (int k = 0; k < 49; ++k) {
                    int idx = k * 256 + tid;
                    if (idx < 6272)
                        hstage[idx] = __hip_atomic_load(hR + idx,
                            __ATOMIC_RELAXED, __HIP_MEMORY_SCOPE_AGENT);
                    else
                        ystage[idx - 6272] = __hip_atomic_load(yR + idx - 6272,
                            __ATOMIC_RELAXED, __HIP_MEMORY_SCOPE_AGENT);
                }
            } else {
                #pragma unroll
                for (int k = 0; k < 24; ++k) {
                    int idx = k * 256 + tid;
                    hstage[idx] = __hip_atomic_load(hR + idx,
                        __ATOMIC_RELAXED, __HIP_MEMORY_SCOPE_AGENT);
                }
                if (tid < 128)
                    hstage[6144 + tid] = __hip_atomic_load(hR + 6144 + tid,
                        __ATOMIC_RELAXED, __HIP_MEMORY_SCOPE_AGENT);
                const uint32* inp32 = (const uint32*)inp + (size_t)t * 32 * 128;
                #pragma unroll
                for (int k = 0; k < 16; ++k) {
                    int i = k * 256 + tid;
                    int row = i >> 7, col = i & 127;
                    ((uint32*)ist)[row * 132 + col] = inp32[row * 128 + col];
                }
            }
            __syncthreads();

            f4v cHH = {0.f, 0.f, 0.f, 0.f}, cLH = cHH, cHL = cHH;
            #pragma unroll
            for (int kt = 0; kt < 12; ++kt) {
                const int co = kt * 16 + quad * 4;
                s8v Ah = *(const s8v*)&hs32[Mrow * 196 + co];
                s8v Al = *(const s8v*)&hs32[HPLANE + Mrow * 196 + co];
                cHH = __builtin_amdgcn_mfma_f32_16x16x32_bf16(Ah, Bhi[kt], cHH, 0, 0, 0);
                cLH = __builtin_amdgcn_mfma_f32_16x16x32_bf16(Al, Bhi[kt], cLH, 0, 0, 0);
                cHL = __builtin_amdgcn_mfma_f32_16x16x32_bf16(Ah, Blo[kt], cHL, 0, 0, 0);
            }
            if (l) {
                #pragma unroll
                for (int kt = 0; kt < 12; ++kt) {
                    const int co = kt * 16 + quad * 4;
                    s8v Ayh = *(const s8v*)&ys32[Mrow * 196 + co];
                    s8v Ayl = *(const s8v*)&ys32[HPLANE + Mrow * 196 + co];
                    s8v Bxh = *(const s8v*)&wlds[n * 392 + kt * 32 + quad * 8];
                    s8v Bxl = *(const s8v*)&wlds[32 * 392 + n * 392 + kt * 32 + quad * 8];
                    cHH = __builtin_amdgcn_mfma_f32_16x16x32_bf16(Ayh, Bxh, cHH, 0, 0, 0);
                    cLH = __builtin_amdgcn_mfma_f32_16x16x32_bf16(Ayl, Bxh, cLH, 0, 0, 0);
                    cHL = __builtin_amdgcn_mfma_f32_16x16x32_bf16(Ayh, Bxl, cHL, 0, 0, 0);
                }
            } else {
                #pragma unroll
                for (int kt = 0; kt < 8; ++kt) {
                    s8v Ai = *(const s8v*)&ist[Mrow * 264 + kt * 32 + quad * 8];
                    s8v Bxh = *(const s8v*)&wlds[n * 264 + kt * 32 + quad * 8];
                    s8v Bxl = *(const s8v*)&wlds[32 * 264 + n * 264 + kt * 32 + quad * 8];
                    cHH = __builtin_amdgcn_mfma_f32_16x16x32_bf16(Ai, Bxh, cHH, 0, 0, 0);
                    cHL = __builtin_amdgcn_mfma_f32_16x16x32_bf16(Ai, Bxl, cHL, 0, 0, 0);
                }
            }
            #pragma unroll
            for (int rr = 0; rr < 4; ++rr)
                gates[n * 33 + mtile * 16 + quad * 4 + rr] =
                    cHH[rr] + cLH[rr] + cHL[rr];
            __syncthreads();

            if (tid < 128) {
                const int jj0 = 2 * jp, jj1 = 2 * jp + 1;
                float pi0 = gates[jj0 * 33 + ub]        + bI0;
                float pf0 = gates[(8 + jj0) * 33 + ub]  + bF0;
                float pg0 = gates[(16 + jj0) * 33 + ub] + bG0;
                float po0 = gates[(24 + jj0) * 33 + ub] + bO0;
                float pi1 = gates[jj1 * 33 + ub]        + bI1;
                float pf1 = gates[(8 + jj1) * 33 + ub]  + bF1;
                float pg1 = gates[(16 + jj1) * 33 + ub] + bG1;
                float po1 = gates[(24 + jj1) * 33 + ub] + bO1;
                c0r = sigmoidf(pf0) * c0r + sigmoidf(pi0) * fast_tanh(pg0);
                c1r = sigmoidf(pf1) * c1r + sigmoidf(pi1) * fast_tanh(pg1);
                float hv0 = sigmoidf(po0) * fast_tanh(c0r);
                float hv1 = sigmoidf(po1) * fast_tanh(c1r);
                h0l = hv0; h1l = hv1;
                bf16u h0h = f2bf(hv0); bf16u h0lo = f2bf(hv0 - bf2f(h0h));
                bf16u h1h = f2bf(hv1); bf16u h1lo = f2bf(hv1 - bf2f(h1h));
                __hip_atomic_store(&hW[ub * 196 + wcol],
                                   (uint32)h0h | ((uint32)h1h << 16),
                                   __ATOMIC_RELAXED, __HIP_MEMORY_SCOPE_AGENT);
                __hip_atomic_store(&hW[HPLANE + ub * 196 + wcol],
                                   (uint32)h0lo | ((uint32)h1lo << 16),
                                   __ATOMIC_RELAXED, __HIP_MEMORY_SCOPE_AGENT);
                if (l == 3)
                    *(uint32*)(y3 + ((size_t)t * 32 + ub) * 384 + jg0) =
                        (uint32)h0h | ((uint32)h1h << 16);
            }
        }
        flag_barrier(flags, (uint32)(r + 2), tid, bid);
    }

    if (tid < 128) {
        hs_out[(size_t)l * 12288 + ub * 384 + jg0]     = h0l;
        hs_out[(size_t)l * 12288 + ub * 384 + jg0 + 1] = h1l;
        cs_out[(size_t)l * 12288 + ub * 384 + jg0]     = c0r;
        cs_out[(size_t)l * 12288 + ub * 384 + jg0 + 1] = c1r;
    }
}

// ---------------------------------------------------------------------------
// Causal flash attention, bf16 in/out (unchanged from passing rounds).
// ---------------------------------------------------------------------------
__global__ void __launch_bounds__(256) attn_kernel(
    const bf16u* __restrict__ outy, const bf16u* __restrict__ keys,
    bf16u* __restrict__ ctxv)
{
    const int b = blockIdx.y;
    const int q0 = blockIdx.x * 32;
    const int tid = threadIdx.x;
    __shared__ uint32 Qs[32][194];
    __shared__ uint32 Ks[16][194];
    __shared__ uint32 Vs[16][192];
    __shared__ float Ss[32][16];
    __shared__ float m_s[32], l_s[32], alpha_s[32];

    for (int i = tid; i < 32 * 192; i += 256) {
        int q = i / 192, dp = i - q * 192;
        Qs[q][dp] = ((const uint32*)(outy + ((size_t)(q0 + q) * 32 + b) * 384))[dp];
    }
    if (tid < 32) { m_s[tid] = -3e38f; l_s[tid] = 0.f; }

    const int qo = tid >> 3, dg = tid & 7;
    float O[48];
    #pragma unroll
    for (int d = 0; d < 48; ++d) O[d] = 0.f;

    const int nkt = (q0 + 32) >> 4;
    for (int kt = 0; kt < nkt; ++kt) {
        const int k0 = kt * 16;
        __syncthreads();
        for (int i = tid; i < 16 * 192; i += 256) {
            int kk = i / 192, dp = i - kk * 192;
            size_t rt = (size_t)(k0 + kk) * 32 + b;
            Ks[kk][dp] = ((const uint32*)(keys + rt * 384))[dp];
            Vs[kk][dp] = ((const uint32*)(outy + rt * 384))[dp];
        }
        __syncthreads();
        #pragma unroll
        for (int pp = 0; pp < 2; ++pp) {
            int p = tid + pp * 256;
            int q = p >> 4, k = p & 15;
            const uint32* qrow = Qs[q];
            const uint32* krow = Ks[k];
            float acc = 0.f;
            for (int dp = 0; dp < 192; ++dp) {
                uint32 qa = qrow[dp], ka = krow[dp];
                acc = fmaf(bflo(qa), bflo(ka), acc);
                acc = fmaf(bfhi(qa), bfhi(ka), acc);
            }
            acc *= 0.051031036307982884f;    // 1/sqrt(384)
            Ss[q][k] = ((k0 + k) <= (q0 + q)) ? acc : -1e30f;
        }
        __syncthreads();
        if (tid < 32) {
            int q = tid;
            float mt = m_s[q];
            #pragma unroll
            for (int k = 0; k < 16; ++k) mt = fmaxf(mt, Ss[q][k]);
            float alpha = __expf(m_s[q] - mt);
            float l = l_s[q] * alpha;
            #pragma unroll
            for (int k = 0; k < 16; ++k) {
                float pv = __expf(Ss[q][k] - mt);
                Ss[q][k] = pv;
                l += pv;
            }
            m_s[q] = mt; l_s[q] = l; alpha_s[q] = alpha;
        }
        __syncthreads();
        {
            float al = alpha_s[qo];
            #pragma unroll
            for (int d = 0; d < 48; ++d) O[d] *= al;
            for (int k = 0; k < 16; ++k) {
                float pv = Ss[qo][k];
                const uint32* vrow = Vs[k] + dg * 24;
                #pragma unroll
                for (int dp = 0; dp < 24; ++dp) {
                    uint32 va = vrow[dp];
                    O[2 * dp]     = fmaf(pv, bflo(va), O[2 * dp]);
                    O[2 * dp + 1] = fmaf(pv, bfhi(va), O[2 * dp + 1]);
                }
            }
        }
    }
    float inv = 1.f / l_s[qo];
    uint32* dst = (uint32*)(ctxv + ((size_t)(q0 + qo) * 32 + b) * 384) + dg * 24;
    #pragma unroll
    for (int dp = 0; dp < 24; ++dp)
        dst[dp] = pack2bf(O[2 * dp] * inv, O[2 * dp + 1] * inv);
}

// ---------------------------------------------------------------------------
extern "C" void kernel_launch(void* const* d_in, const int* in_sizes, int n_in,
                              void* d_out, int out_size, void* d_ws, size_t ws_size,
                              hipStream_t stream) {
    (void)in_sizes; (void)n_in; (void)out_size; (void)ws_size;
    const int*   x        = (const int*)d_in[0];
    const float* context  = (const float*)d_in[1];
    const float* h_in     = (const float*)d_in[2];
    const float* c_in     = (const float*)d_in[3];
    const float* emb      = (const float*)d_in[4];
    const float* ctx_W    = (const float*)d_in[5];
    const float* ctx_b    = (const float*)d_in[6];
    const float* Wih0     = (const float*)d_in[7];
    const float* Wih_rest = (const float*)d_in[8];
    const float* Whh      = (const float*)d_in[9];
    const float* bih      = (const float*)d_in[10];
    const float* bhh      = (const float*)d_in[11];
    const float* Wa       = (const float*)d_in[12];
    const float* comb_W   = (const float*)d_in[13];
    const float* comb_b   = (const float*)d_in[14];
    const float* fc_W     = (const float*)d_in[15];
    const float* fc_b     = (const float*)d_in[16];
    float* out = (float*)d_out;

    // ---- workspace layout, ~76 MB peak ----
    char* wsb = (char*)d_ws;
    uint32* flags = (uint32*)(wsb + 0);               // 24.6 KB (192 lines)
    uint32* hbuf  = (uint32*)(wsb + 32768);           // 401 KB [4][2][2][32][196]
    bf16u*  y3    = (bf16u*)(wsb + 524288);           // 25.17 MB
    bf16u*  keysu = (bf16u*)(wsb + 25690112ull);      // 25.17 MB
    bf16u*  inp   = (bf16u*)(wsb + 50855936ull);      // 16.78 MB
    bf16u*  ctxvu = (bf16u*)(wsb + 50855936ull);      // reuse (inp dead)
    bf16u*  combu = keysu;                            // reuse (keys dead)

    hipMemsetAsync(d_ws, 0, 32768, stream);           // zero flags

    static int smem_set = 0;
    if (!smem_set) {
        hipFuncSetAttribute((const void*)lstm_wave_kernel,
                            hipFuncAttributeMaxDynamicSharedMemorySize, 155648);
        smem_set = 1;
    }

    embed_ctx_kernel<<<2048, 128, 0, stream>>>(x, context, emb, ctx_W, ctx_b, inp);

    const size_t HS_OFF = (size_t)32768 * 100;
    lstm_wave_kernel<<<192, 256, 154752, stream>>>(
        inp, Wih0, Wih_rest, Whh, bih, bhh, h_in, c_in,
        y3, hbuf, flags, out + HS_OFF, out + HS_OFF + 49152);

    // keys = y3 @ Wa^T
    gemm_kernel<<<dim3(6, 512), 256, 0, stream>>>(
        y3, nullptr, 384, Wa, nullptr, keysu, 32768, 384, 384, 1);
    // ctx_vec (flash attention)
    attn_kernel<<<dim3(32, 32), 256, 0, stream>>>(y3, keysu, ctxvu);
    // combined = tanh([y3, ctx] @ comb_W^T + b)  -> keys region
    gemm_kernel<<<dim3(6, 512), 256, 0, stream>>>(
        y3, ctxvu, 384, comb_W, comb_b, combu, 32768, 384, 768, 2);
    // logits = combined @ fc_W^T + fc_b  -> d_out permuted [b][t][100]
    gemm_kernel<<<dim3(2, 512), 256, 0, stream>>>(
        combu, nullptr, 384, fc_W, fc_b, out, 32768, 100, 384, 3);
}

// Round 9
// 13609.146 us; speedup vs baseline: 4.4892x; 1.0932x over previous
//
#include <hip/hip_runtime.h>

typedef unsigned int  uint32;
typedef unsigned long long u64;
typedef unsigned short bf16u;
typedef __attribute__((ext_vector_type(8))) short s8v;    // 8 bf16 (4 VGPRs)
typedef __attribute__((ext_vector_type(4))) float f4v;    // MFMA acc

#define PL   6144            // u32 per plane  (48 sub * 32 b * 4 u32)
#define PAR  12288           // u32 per parity (2 planes)
#define HB2  24576           // u32 per layer  (2 parities)

__device__ __forceinline__ float fast_tanh(float x) {
    x = fminf(9.f, fmaxf(-9.f, x));
    float e = __expf(2.f * x);
    return (e - 1.f) / (e + 1.f);
}
__device__ __forceinline__ float sigmoidf(float x) {
    return 1.f / (1.f + __expf(-x));
}
__device__ __forceinline__ bf16u f2bf(float f) {
    uint32 u = __float_as_uint(f);
    u += 0x7fffu + ((u >> 16) & 1u);
    return (bf16u)(u >> 16);
}
__device__ __forceinline__ float bf2f(bf16u u) {
    return __uint_as_float(((uint32)u) << 16);
}
__device__ __forceinline__ uint32 pack2bf(float lo, float hi) {
    return (uint32)f2bf(lo) | ((uint32)f2bf(hi) << 16);
}
__device__ __forceinline__ float bflo(uint32 p) { return __uint_as_float(p << 16); }
__device__ __forceinline__ float bfhi(uint32 p) { return __uint_as_float(p & 0xffff0000u); }

// ---------------------------------------------------------------------------
// Embedding + context projection -> inp [rt=t*32+b][256] bf16 (emb || ctx)
// ---------------------------------------------------------------------------
__global__ void __launch_bounds__(128) embed_ctx_kernel(
    const int* __restrict__ x, const float* __restrict__ ctx,
    const float* __restrict__ emb, const float* __restrict__ ctxW,
    const float* __restrict__ ctxb, bf16u* __restrict__ inp)
{
    const int r0 = blockIdx.x * 16;
    const int tid = threadIdx.x;
    __shared__ float cs[16][301];
    __shared__ int xs[16];
    for (int i = tid; i < 16 * 300; i += 128) {
        int row = i / 300, k = i - row * 300;
        int rt = r0 + row, b = rt & 31, t = rt >> 5;
        cs[row][k] = ctx[((size_t)b * 1024 + t) * 300 + k];
    }
    if (tid < 16) {
        int rt = r0 + tid;
        xs[tid] = x[(rt & 31) * 1024 + (rt >> 5)];
    }
    __syncthreads();
    float acc[16];
    #pragma unroll
    for (int row = 0; row < 16; ++row) acc[row] = 0.f;
    for (int k = 0; k < 300; ++k) {
        float w = ctxW[tid * 300 + k];
        #pragma unroll
        for (int row = 0; row < 16; ++row) acc[row] = fmaf(w, cs[row][k], acc[row]);
    }
    float bb = ctxb[tid];
    for (int row = 0; row < 16; ++row) {
        size_t base = (size_t)(r0 + row) * 256;
        inp[base + tid]       = f2bf(emb[xs[row] * 128 + tid]);
        inp[base + 128 + tid] = f2bf(acc[row] + bb);
    }
}

// ---------------------------------------------------------------------------
// MFMA GEMM: C[M,N] = A[M,K](bf16) @ W[N,K]^T(f32, split hi/lo bf16)
// A split at K0 between A0/A1. mode 1: bf16 out; 2: bf16+tanh;
// 3: f32 out, row rt->(b*1024+t) (logits). BM=BN=64, BK=32.
// ---------------------------------------------------------------------------
__global__ void __launch_bounds__(256) gemm_kernel(
    const bf16u* __restrict__ A0, const bf16u* __restrict__ A1, int K0,
    const float* __restrict__ W, const float* __restrict__ bias1,
    void* __restrict__ Cout, int M, int N, int K, int mode)
{
    __shared__ bf16u As[64][40];
    __shared__ bf16u Whi[64][40];
    __shared__ bf16u Wlo[64][40];
    const int tid = threadIdx.x;
    const int bn = blockIdx.x * 64, bm = blockIdx.y * 64;
    const int wave = tid >> 6, lane = tid & 63;
    const int wm = wave >> 1, wn = wave & 1;
    const int ncol = lane & 15, quad = lane >> 4;
    const int lr = tid >> 2, lk = (tid & 3) * 8;

    f4v acc[2][2];
    #pragma unroll
    for (int i = 0; i < 2; ++i)
        #pragma unroll
        for (int j = 0; j < 2; ++j) acc[i][j] = (f4v){0.f, 0.f, 0.f, 0.f};

    const int wrow = bn + lr;
    for (int k0 = 0; k0 < K; k0 += 32) {
        const bf16u* Ab; int kb, lda;
        if (k0 < K0) { Ab = A0; kb = k0; lda = K0; }
        else         { Ab = A1; kb = k0 - K0; lda = K - K0; }
        uint4 av = *(const uint4*)(Ab + (size_t)(bm + lr) * lda + kb + lk);
        float4 w0 = make_float4(0.f, 0.f, 0.f, 0.f), w1 = w0;
        if (wrow < N) {
            const float* wp = W + (size_t)wrow * K + k0 + lk;
            w0 = *(const float4*)wp;
            w1 = *(const float4*)(wp + 4);
        }
        __syncthreads();
        *(uint4*)&As[lr][lk] = av;
        {
            bf16u h[8], l[8];
            float wf[8] = {w0.x, w0.y, w0.z, w0.w, w1.x, w1.y, w1.z, w1.w};
            #pragma unroll
            for (int j = 0; j < 8; ++j) {
                h[j] = f2bf(wf[j]);
                l[j] = f2bf(wf[j] - bf2f(h[j]));
            }
            #pragma unroll
            for (int j = 0; j < 8; ++j) Whi[lr][lk + j] = h[j];
            #pragma unroll
            for (int j = 0; j < 8; ++j) Wlo[lr][lk + j] = l[j];
        }
        __syncthreads();
        s8v aF[2], bH[2], bL[2];
        #pragma unroll
        for (int mt = 0; mt < 2; ++mt)
            aF[mt] = *(const s8v*)&As[wm * 32 + mt * 16 + ncol][quad * 8];
        #pragma unroll
        for (int nt = 0; nt < 2; ++nt) {
            bH[nt] = *(const s8v*)&Whi[wn * 32 + nt * 16 + ncol][quad * 8];
            bL[nt] = *(const s8v*)&Wlo[wn * 32 + nt * 16 + ncol][quad * 8];
        }
        #pragma unroll
        for (int mt = 0; mt < 2; ++mt)
            #pragma unroll
            for (int nt = 0; nt < 2; ++nt) {
                acc[mt][nt] = __builtin_amdgcn_mfma_f32_16x16x32_bf16(
                    aF[mt], bH[nt], acc[mt][nt], 0, 0, 0);
                acc[mt][nt] = __builtin_amdgcn_mfma_f32_16x16x32_bf16(
                    aF[mt], bL[nt], acc[mt][nt], 0, 0, 0);
            }
    }

    #pragma unroll
    for (int nt = 0; nt < 2; ++nt) {
        const int col = bn + wn * 32 + nt * 16 + ncol;
        if (col >= N) continue;
        float bb = bias1 ? bias1[col] : 0.f;
        #pragma unroll
        for (int mt = 0; mt < 2; ++mt) {
            const int rowb = bm + wm * 32 + mt * 16 + quad * 4;
            if (mode == 3) {
                #pragma unroll
                for (int r = 0; r < 4; ++r) {
                    int row = rowb + r;
                    int b = row & 31, t = row >> 5;
                    ((float*)Cout)[((size_t)b * 1024 + t) * (size_t)N + col] =
                        acc[mt][nt][r] + bb;
                }
            } else {
                #pragma unroll
                for (int r = 0; r < 4; ++r) {
                    float v = acc[mt][nt][r] + bb;
                    if (mode == 2) v = fast_tanh(v);
                    ((bf16u*)Cout)[(size_t)(rowb + r) * N + col] = f2bf(v);
                }
            }
        }
    }
}

// ---------------------------------------------------------------------------
// Flag barrier, 192 blocks, one flag per 128-B line.
// __syncthreads() before the store drains vmcnt(0) -> prior agent-scope
// h-stores are at the coherence point before the flag becomes visible.
// ---------------------------------------------------------------------------
__device__ __forceinline__ void flag_barrier(uint32* flags, uint32 r,
                                             int tid, int bid) {
    __syncthreads();
    if (tid == 0)
        __hip_atomic_store(&flags[bid * 32], r, __ATOMIC_RELAXED, __HIP_MEMORY_SCOPE_AGENT);
    if (tid < 192) {
        while (__hip_atomic_load(&flags[tid * 32], __ATOMIC_RELAXED,
                                 __HIP_MEMORY_SCOPE_AGENT) < r)
            __builtin_amdgcn_s_sleep(1);
    }
    __syncthreads();
}

// ---------------------------------------------------------------------------
// Layer-wavefront LSTM: all 4 layers x 1024 steps, ONE launch, 1027 rounds.
// 192 blocks = 4 layers x 48 sub-blocks x 8 hidden dims.
// h broadcast layout is BLOCK-MAJOR DENSE: [layer][parity][plane][sub][b][4u32]
// -> each block's per-round stores are full 128-B lines (no HBM RMW).
// MFMA k-order is preserved (j = sub*8+d is natural order): A-frag for
// k-chunk (kt,quad) = 16 contiguous bytes at [(kt*4+quad)*32 + Mrow]*16B.
// Layer-3 output y3 also block-major ([t][sub][b][4u32]); transposed to
// standard layout by a separate kernel afterwards.
// ---------------------------------------------------------------------------
__global__ void __launch_bounds__(256, 1) lstm_wave_kernel(
    const bf16u* __restrict__ inp,   // [t*32+b][256] bf16
    const float* __restrict__ Wih0,  // [1536][256]
    const float* __restrict__ WihR,  // [3][1536][384]
    const float* __restrict__ Whh,   // [4][1536][384]
    const float* __restrict__ bih, const float* __restrict__ bhh,
    const float* __restrict__ h_in, const float* __restrict__ c_in,
    uint32* __restrict__ y3bm,       // [1024][48][32][4] u32 (hi plane only)
    uint32* __restrict__ hbuf,       // [4][2][2][48][32][4] u32
    uint32* __restrict__ flags,
    float* __restrict__ hs_out, float* __restrict__ cs_out)
{
    extern __shared__ char sm[];
    const int tid = threadIdx.x, bid = blockIdx.x;
    const int l = bid / 48, sub = bid - l * 48;
    const int j0 = sub * 8;
    const int wave = tid >> 6, lane = tid & 63;
    const int ntile = wave & 1, mtile = wave >> 1;
    const int ncol = lane & 15, quad = lane >> 4;
    const int n = ntile * 16 + ncol;                 // local gate-row 0..31
    const int gsel = n >> 3, jln = n & 7;
    const int Mrow = mtile * 16 + ncol;

    const int Kx = l ? 384 : 256;
    const int WSTR = l ? 392 : 264;                  // padded bf16 stride
    const int wbytes = 2 * 32 * WSTR * 2;            // Wih planes bytes
    bf16u* wlds  = (bf16u*)sm;
    u64*  hstage = (u64*)(sm + wbytes);              // 49152 B
    u64*  ystage = (u64*)(sm + wbytes + 49152);      // 49152 (l>0) / 16896 (ist)
    float* gates = (float*)(sm + wbytes + 49152 + (l ? 49152 : 16896));
    uint32* hs32 = (uint32*)hstage;
    uint32* ys32 = (uint32*)ystage;
    bf16u*  ist  = (bf16u*)ystage;

    const float* WhhL = Whh + (size_t)l * 1536 * 384;
    const float* WihL = l ? (WihR + (size_t)(l - 1) * 1536 * 384) : Wih0;
    const float* bihL = bih + l * 1536;
    const float* bhhL = bhh + l * 1536;
    uint32* hbL = hbuf + (size_t)l * HB2;
    uint32* ybL = l ? (hbuf + (size_t)(l - 1) * HB2) : nullptr;

    // ---- Whh B-frags in registers (hi/lo), rows = this block's 32 gates ----
    s8v Bhi[12], Blo[12];
    {
        const int wrow = gsel * 384 + j0 + jln;
        #pragma unroll
        for (int kt = 0; kt < 12; ++kt) {
            const float* wp = WhhL + (size_t)wrow * 384 + kt * 32 + quad * 8;
            s8v hi, lo;
            #pragma unroll
            for (int j = 0; j < 8; ++j) {
                float w = wp[j];
                bf16u wh = f2bf(w);
                bf16u wl = f2bf(w - bf2f(wh));
                hi[j] = (short)wh; lo[j] = (short)wl;
            }
            Bhi[kt] = hi; Blo[kt] = lo;
        }
    }
    // ---- Wih slice into LDS (hi/lo planes) ----
    for (int r2 = 0; r2 < 32; ++r2) {
        int rg = (r2 >> 3) * 384 + j0 + (r2 & 7);
        for (int k = tid; k < Kx; k += 256) {
            float w = WihL[(size_t)rg * Kx + k];
            bf16u wh = f2bf(w);
            wlds[r2 * WSTR + k] = wh;
            wlds[32 * WSTR + r2 * WSTR + k] = f2bf(w - bf2f(wh));
        }
    }

    // update role: tid<128 owns (batch ub, dim pair jg0, jg0+1)
    const int ub = tid & 31, jp = tid >> 5;          // jp 0..3 for tid<128
    const int jg0 = j0 + 2 * jp;
    const int wbase = (sub * 32 + ub) * 4 + jp;      // dense u32 index
    float c0r = 0.f, c1r = 0.f, h0l = 0.f, h1l = 0.f;
    float bI0 = 0, bF0 = 0, bG0 = 0, bO0 = 0, bI1 = 0, bF1 = 0, bG1 = 0, bO1 = 0;

    if (tid < 128) {
        bI0 = bihL[jg0] + bhhL[jg0];
        bF0 = bihL[384 + jg0] + bhhL[384 + jg0];
        bG0 = bihL[768 + jg0] + bhhL[768 + jg0];
        bO0 = bihL[1152 + jg0] + bhhL[1152 + jg0];
        bI1 = bihL[jg0 + 1] + bhhL[jg0 + 1];
        bF1 = bihL[384 + jg0 + 1] + bhhL[384 + jg0 + 1];
        bG1 = bihL[768 + jg0 + 1] + bhhL[768 + jg0 + 1];
        bO1 = bihL[1152 + jg0 + 1] + bhhL[1152 + jg0 + 1];
        float ha = h_in[(size_t)l * 12288 + ub * 384 + jg0];
        float hb = h_in[(size_t)l * 12288 + ub * 384 + jg0 + 1];
        bf16u ha_h = f2bf(ha); bf16u ha_l = f2bf(ha - bf2f(ha_h));
        bf16u hb_h = f2bf(hb); bf16u hb_l = f2bf(hb - bf2f(hb_h));
        __hip_atomic_store(&hbL[wbase],
                           (uint32)ha_h | ((uint32)hb_h << 16),
                           __ATOMIC_RELAXED, __HIP_MEMORY_SCOPE_AGENT);
        __hip_atomic_store(&hbL[PL + wbase],
                           (uint32)ha_l | ((uint32)hb_l << 16),
                           __ATOMIC_RELAXED, __HIP_MEMORY_SCOPE_AGENT);
        c0r = c_in[(size_t)l * 12288 + ub * 384 + jg0];
        c1r = c_in[(size_t)l * 12288 + ub * 384 + jg0 + 1];
    }
    flag_barrier(flags, 1u, tid, bid);

    for (int r = 0; r < 1027; ++r) {
        const int t = r - l;
        if ((unsigned)t < 1024u) {
            const u64* hR64 = (const u64*)(hbL + (t & 1) * PAR);
            uint32* hW = hbL + ((t + 1) & 1) * PAR;

            // ---- stage h (and y / inp) -> LDS, dense contiguous copies ----
            #pragma unroll
            for (int k = 0; k < 24; ++k) {
                int idx = k * 256 + tid;
                hstage[idx] = __hip_atomic_load(hR64 + idx,
                    __ATOMIC_RELAXED, __HIP_MEMORY_SCOPE_AGENT);
            }
            if (l) {
                const u64* yR64 = (const u64*)(ybL + ((t + 1) & 1) * PAR);
                #pragma unroll
                for (int k = 0; k < 24; ++k) {
                    int idx = k * 256 + tid;
                    ystage[idx] = __hip_atomic_load(yR64 + idx,
                        __ATOMIC_RELAXED, __HIP_MEMORY_SCOPE_AGENT);
                }
            } else {
                const uint32* inp32 = (const uint32*)inp + (size_t)t * 32 * 128;
                #pragma unroll
                for (int k = 0; k < 16; ++k) {
                    int i = k * 256 + tid;
                    int row = i >> 7, col = i & 127;
                    ((uint32*)ist)[row * 132 + col] = inp32[row * 128 + col];
                }
            }
            __syncthreads();

            // ---- MFMA: gates[32 rows x 32 b], hi/lo split fp32-fidelity ----
            f4v cHH = {0.f, 0.f, 0.f, 0.f}, cLH = cHH, cHL = cHH;
            #pragma unroll
            for (int kt = 0; kt < 12; ++kt) {
                const int co = ((kt * 4 + quad) * 32 + Mrow) * 4;
                s8v Ah = *(const s8v*)&hs32[co];
                s8v Al = *(const s8v*)&hs32[PL + co];
                cHH = __builtin_amdgcn_mfma_f32_16x16x32_bf16(Ah, Bhi[kt], cHH, 0, 0, 0);
                cLH = __builtin_amdgcn_mfma_f32_16x16x32_bf16(Al, Bhi[kt], cLH, 0, 0, 0);
                cHL = __builtin_amdgcn_mfma_f32_16x16x32_bf16(Ah, Blo[kt], cHL, 0, 0, 0);
            }
            if (l) {
                #pragma unroll
                for (int kt = 0; kt < 12; ++kt) {
                    const int co = ((kt * 4 + quad) * 32 + Mrow) * 4;
                    s8v Ayh = *(const s8v*)&ys32[co];
                    s8v Ayl = *(const s8v*)&ys32[PL + co];
                    s8v Bxh = *(const s8v*)&wlds[n * 392 + kt * 32 + quad * 8];
                    s8v Bxl = *(const s8v*)&wlds[32 * 392 + n * 392 + kt * 32 + quad * 8];
                    cHH = __builtin_amdgcn_mfma_f32_16x16x32_bf16(Ayh, Bxh, cHH, 0, 0, 0);
                    cLH = __builtin_amdgcn_mfma_f32_16x16x32_bf16(Ayl, Bxh, cLH, 0, 0, 0);
                    cHL = __builtin_amdgcn_mfma_f32_16x16x32_bf16(Ayh, Bxl, cHL, 0, 0, 0);
                }
            } else {
                #pragma unroll
                for (int kt = 0; kt < 8; ++kt) {
                    s8v Ai = *(const s8v*)&ist[Mrow * 264 + kt * 32 + quad * 8];
                    s8v Bxh = *(const s8v*)&wlds[n * 264 + kt * 32 + quad * 8];
                    s8v Bxl = *(const s8v*)&wlds[32 * 264 + n * 264 + kt * 32 + quad * 8];
                    cHH = __builtin_amdgcn_mfma_f32_16x16x32_bf16(Ai, Bxh, cHH, 0, 0, 0);
                    cHL = __builtin_amdgcn_mfma_f32_16x16x32_bf16(Ai, Bxl, cHL, 0, 0, 0);
                }
            }
            #pragma unroll
            for (int rr = 0; rr < 4; ++rr)
                gates[n * 33 + mtile * 16 + quad * 4 + rr] =
                    cHH[rr] + cLH[rr] + cHL[rr];
            __syncthreads();

            // ---- cell update: tid<128, 2 dims each; DENSE h stores ----
            if (tid < 128) {
                const int jj0 = 2 * jp, jj1 = 2 * jp + 1;
                float pi0 = gates[jj0 * 33 + ub]        + bI0;
                float pf0 = gates[(8 + jj0) * 33 + ub]  + bF0;
                float pg0 = gates[(16 + jj0) * 33 + ub] + bG0;
                float po0 = gates[(24 + jj0) * 33 + ub] + bO0;
                float pi1 = gates[jj1 * 33 + ub]        + bI1;
                float pf1 = gates[(8 + jj1) * 33 + ub]  + bF1;
                float pg1 = gates[(16 + jj1) * 33 + ub] + bG1;
                float po1 = gates[(24 + jj1) * 33 + ub] + bO1;
                c0r = sigmoidf(pf0) * c0r + sigmoidf(pi0) * fast_tanh(pg0);
                c1r = sigmoidf(pf1) * c1r + sigmoidf(pi1) * fast_tanh(pg1);
                float hv0 = sigmoidf(po0) * fast_tanh(c0r);
                float hv1 = sigmoidf(po1) * fast_tanh(c1r);
                h0l = hv0; h1l = hv1;
                bf16u h0h = f2bf(hv0); bf16u h0lo = f2bf(hv0 - bf2f(h0h));
                bf16u h1h = f2bf(hv1); bf16u h1lo = f2bf(hv1 - bf2f(h1h));
                uint32 hiw = (uint32)h0h | ((uint32)h1h << 16);
                uint32 low = (uint32)h0lo | ((uint32)h1lo << 16);
                __hip_atomic_store(&hW[wbase], hiw,
                                   __ATOMIC_RELAXED, __HIP_MEMORY_SCOPE_AGENT);
                __hip_atomic_store(&hW[PL + wbase], low,
                                   __ATOMIC_RELAXED, __HIP_MEMORY_SCOPE_AGENT);
                if (l == 3)
                    y3bm[(size_t)t * 6144 + wbase] = hiw;   // dense full lines
            }
        }
        flag_barrier(flags, (uint32)(r + 2), tid, bid);
    }

    if (tid < 128) {
        hs_out[(size_t)l * 12288 + ub * 384 + jg0]     = h0l;
        hs_out[(size_t)l * 12288 + ub * 384 + jg0 + 1] = h1l;
        cs_out[(size_t)l * 12288 + ub * 384 + jg0]     = c0r;
        cs_out[(size_t)l * 12288 + ub * 384 + jg0 + 1] = c1r;
    }
}

// ---------------------------------------------------------------------------
// y3 block-major [t][48][32][4u32] -> standard [t*32+b][384] bf16.
// One block per t; LDS transpose, coalesced both sides.
// ---------------------------------------------------------------------------
__global__ void __launch_bounds__(256) transpose_y_kernel(
    const uint32* __restrict__ in, uint32* __restrict__ out)
{
    const int t = blockIdx.x;
    const int tid = threadIdx.x;
    __shared__ uint32 lds[32 * 197];
    const uint32* src = in + (size_t)t * 6144;
    #pragma unroll
    for (int k = 0; k < 24; ++k) {
        int i = k * 256 + tid;
        int sub = i >> 7, b = (i >> 2) & 31, q = i & 3;
        lds[b * 197 + sub * 4 + q] = src[i];
    }
    __syncthreads();
    uint32* dst = out + (size_t)t * 32 * 192;
    #pragma unroll
    for (int k = 0; k < 24; ++k) {
        int i = k * 256 + tid;
        int b = i / 192, c = i - b * 192;
        dst[b * 192 + c] = lds[b * 197 + c];
    }
}

// ---------------------------------------------------------------------------
// Causal flash attention, bf16 in/out (unchanged from passing rounds).
// ---------------------------------------------------------------------------
__global__ void __launch_bounds__(256) attn_kernel(
    const bf16u* __restrict__ outy, const bf16u* __restrict__ keys,
    bf16u* __restrict__ ctxv)
{
    const int b = blockIdx.y;
    const int q0 = blockIdx.x * 32;
    const int tid = threadIdx.x;
    __shared__ uint32 Qs[32][194];
    __shared__ uint32 Ks[16][194];
    __shared__ uint32 Vs[16][192];
    __shared__ float Ss[32][16];
    __shared__ float m_s[32], l_s[32], alpha_s[32];

    for (int i = tid; i < 32 * 192; i += 256) {
        int q = i / 192, dp = i - q * 192;
        Qs[q][dp] = ((const uint32*)(outy + ((size_t)(q0 + q) * 32 + b) * 384))[dp];
    }
    if (tid < 32) { m_s[tid] = -3e38f; l_s[tid] = 0.f; }

    const int qo = tid >> 3, dg = tid & 7;
    float O[48];
    #pragma unroll
    for (int d = 0; d < 48; ++d) O[d] = 0.f;

    const int nkt = (q0 + 32) >> 4;
    for (int kt = 0; kt < nkt; ++kt) {
        const int k0 = kt * 16;
        __syncthreads();
        for (int i = tid; i < 16 * 192; i += 256) {
            int kk = i / 192, dp = i - kk * 192;
            size_t rt = (size_t)(k0 + kk) * 32 + b;
            Ks[kk][dp] = ((const uint32*)(keys + rt * 384))[dp];
            Vs[kk][dp] = ((const uint32*)(outy + rt * 384))[dp];
        }
        __syncthreads();
        #pragma unroll
        for (int pp = 0; pp < 2; ++pp) {
            int p = tid + pp * 256;
            int q = p >> 4, k = p & 15;
            const uint32* qrow = Qs[q];
            const uint32* krow = Ks[k];
            float acc = 0.f;
            for (int dp = 0; dp < 192; ++dp) {
                uint32 qa = qrow[dp], ka = krow[dp];
                acc = fmaf(bflo(qa), bflo(ka), acc);
                acc = fmaf(bfhi(qa), bfhi(ka), acc);
            }
            acc *= 0.051031036307982884f;    // 1/sqrt(384)
            Ss[q][k] = ((k0 + k) <= (q0 + q)) ? acc : -1e30f;
        }
        __syncthreads();
        if (tid < 32) {
            int q = tid;
            float mt = m_s[q];
            #pragma unroll
            for (int k = 0; k < 16; ++k) mt = fmaxf(mt, Ss[q][k]);
            float alpha = __expf(m_s[q] - mt);
            float l = l_s[q] * alpha;
            #pragma unroll
            for (int k = 0; k < 16; ++k) {
                float pv = __expf(Ss[q][k] - mt);
                Ss[q][k] = pv;
                l += pv;
            }
            m_s[q] = mt; l_s[q] = l; alpha_s[q] = alpha;
        }
        __syncthreads();
        {
            float al = alpha_s[qo];
            #pragma unroll
            for (int d = 0; d < 48; ++d) O[d] *= al;
            for (int k = 0; k < 16; ++k) {
                float pv = Ss[qo][k];
                const uint32* vrow = Vs[k] + dg * 24;
                #pragma unroll
                for (int dp = 0; dp < 24; ++dp) {
                    uint32 va = vrow[dp];
                    O[2 * dp]     = fmaf(pv, bflo(va), O[2 * dp]);
                    O[2 * dp + 1] = fmaf(pv, bfhi(va), O[2 * dp + 1]);
                }
            }
        }
    }
    float inv = 1.f / l_s[qo];
    uint32* dst = (uint32*)(ctxv + ((size_t)(q0 + qo) * 32 + b) * 384) + dg * 24;
    #pragma unroll
    for (int dp = 0; dp < 24; ++dp)
        dst[dp] = pack2bf(O[2 * dp] * inv, O[2 * dp + 1] * inv);
}

// ---------------------------------------------------------------------------
extern "C" void kernel_launch(void* const* d_in, const int* in_sizes, int n_in,
                              void* d_out, int out_size, void* d_ws, size_t ws_size,
                              hipStream_t stream) {
    (void)in_sizes; (void)n_in; (void)out_size; (void)ws_size;
    const int*   x        = (const int*)d_in[0];
    const float* context  = (const float*)d_in[1];
    const float* h_in     = (const float*)d_in[2];
    const float* c_in     = (const float*)d_in[3];
    const float* emb      = (const float*)d_in[4];
    const float* ctx_W    = (const float*)d_in[5];
    const float* ctx_b    = (const float*)d_in[6];
    const float* Wih0     = (const float*)d_in[7];
    const float* Wih_rest = (const float*)d_in[8];
    const float* Whh      = (const float*)d_in[9];
    const float* bih      = (const float*)d_in[10];
    const float* bhh      = (const float*)d_in[11];
    const float* Wa       = (const float*)d_in[12];
    const float* comb_W   = (const float*)d_in[13];
    const float* comb_b   = (const float*)d_in[14];
    const float* fc_W     = (const float*)d_in[15];
    const float* fc_b     = (const float*)d_in[16];
    float* out = (float*)d_out;

    // ---- workspace layout, ~76 MB peak ----
    char* wsb = (char*)d_ws;
    uint32* flags = (uint32*)(wsb + 0);               //  32 KB (192 lines)
    uint32* hbuf  = (uint32*)(wsb + 32768);           // 393 KB dense block-major
    uint32* y3bm  = (uint32*)(wsb + 458752);          // 25.17 MB [1024][6144]u32
    bf16u*  y3    = (bf16u*)(wsb + 25624576ull);      // 25.17 MB standard layout
    bf16u*  inp   = (bf16u*)(wsb + 50790400ull);      // 16.78 MB (region 25.17)
    bf16u*  keysu = (bf16u*)(wsb + 50790400ull);      // reuse (inp dead post-lstm)
    bf16u*  ctxvu = (bf16u*)(wsb + 458752);           // reuse (y3bm dead post-transpose)
    bf16u*  combu = (bf16u*)(wsb + 50790400ull);      // reuse (keys dead post-attn)

    hipMemsetAsync(d_ws, 0, 32768, stream);           // zero flags

    static int smem_set = 0;
    if (!smem_set) {
        hipFuncSetAttribute((const void*)lstm_wave_kernel,
                            hipFuncAttributeMaxDynamicSharedMemorySize, 155648);
        smem_set = 1;
    }

    embed_ctx_kernel<<<2048, 128, 0, stream>>>(x, context, emb, ctx_W, ctx_b, inp);

    const size_t HS_OFF = (size_t)32768 * 100;
    lstm_wave_kernel<<<192, 256, 152704, stream>>>(
        inp, Wih0, Wih_rest, Whh, bih, bhh, h_in, c_in,
        y3bm, hbuf, flags, out + HS_OFF, out + HS_OFF + 49152);

    transpose_y_kernel<<<1024, 256, 0, stream>>>(y3bm, (uint32*)y3);

    // keys = y3 @ Wa^T
    gemm_kernel<<<dim3(6, 512), 256, 0, stream>>>(
        y3, nullptr, 384, Wa, nullptr, keysu, 32768, 384, 384, 1);
    // ctx_vec (flash attention)
    attn_kernel<<<dim3(32, 32), 256, 0, stream>>>(y3, keysu, ctxvu);
    // combined = tanh([y3, ctx] @ comb_W^T + b)
    gemm_kernel<<<dim3(6, 512), 256, 0, stream>>>(
        y3, ctxvu, 384, comb_W, comb_b, combu, 32768, 384, 768, 2);
    // logits = combined @ fc_W^T + fc_b  -> d_out permuted [b][t][100]
    gemm_kernel<<<dim3(2, 512), 256, 0, stream>>>(
        combu, nullptr, 384, fc_W, fc_b, out, 32768, 100, 384, 3);
}